// Round 14
// baseline (17769.922 us; speedup 1.0000x reference)
//
#include <hip/hip_runtime.h>
#include <hip/hip_bf16.h>

#define N_  4
#define S_  1024
#define K_  4
#define V_  32000
#define C_  1000
#define D_  512
#define NH_ 8
#define NB_ 6
#define HD_ 2048
#define DH_ 64
#define CAP_ 256
#define M_  (N_*S_)   // 4096 rows

typedef __attribute__((ext_vector_type(8))) short short8_t;   // 8 bf16 = 4 VGPR
typedef __attribute__((ext_vector_type(4))) float f32x4_t;

#define MFMA16(a,b,c) __builtin_amdgcn_mfma_f32_16x16x32_bf16((a),(b),(c),0,0,0)

#define HSPLANE ((size_t)M_ * D_)        // elems per split plane of hs

static __device__ __forceinline__ float bfround(float v) {   // RNE to bf16, as float
    unsigned u = __float_as_uint(v);
    u = (u + 0x7FFFu + ((u >> 16) & 1u)) & 0xFFFF0000u;
    return __uint_as_float(u);
}
static __device__ __forceinline__ void split3(float v, unsigned short& a, unsigned short& b, unsigned short& c) {
    const float f0 = bfround(v);      const float r1 = v - f0;
    const float f1 = bfround(r1);     const float f2 = bfround(r1 - f1);
    a = (unsigned short)(__float_as_uint(f0) >> 16);
    b = (unsigned short)(__float_as_uint(f1) >> 16);
    c = (unsigned short)(__float_as_uint(f2) >> 16);
}
static __device__ __forceinline__ unsigned short f2bf(float f) {
    unsigned u = __float_as_uint(f);
    return (unsigned short)((u + 0x7FFFu + ((u >> 16) & 1u)) >> 16);
}
static __device__ __forceinline__ float b2f(unsigned short u) {
    return __uint_as_float((unsigned)u << 16);
}

// ---------------------------------------------------------------- embed
__global__ __launch_bounds__(256) void embed_kernel(const int* __restrict__ x_in,
    const float* __restrict__ tok, const float* __restrict__ pos, float* __restrict__ x)
{
    const int idx = blockIdx.x * 256 + threadIdx.x;
    const int total = M_ * (D_ / 4);
    if (idx >= total) return;
    const int d = (idx & (D_ / 4 - 1)) * 4;
    const int row = idx >> 7;
    const int s = row & (S_ - 1);
    const int t = x_in[row];
    const float4 a = *(const float4*)(tok + (size_t)t * D_ + d);
    const float4 b = *(const float4*)(pos + (size_t)s * D_ + d);
    float4 r; r.x = a.x + b.x; r.y = a.y + b.y; r.z = a.z + b.z; r.w = a.w + b.w;
    *(float4*)(x + (size_t)row * D_ + d) = r;
}

// ---------------------------------------------------------------- layernorm -> split bf16x3 planes (FIN: also write hfin plane0)
template<int FIN>
__global__ __launch_bounds__(256) void ln_kernel(const float* __restrict__ x,
    const float* __restrict__ sc, const float* __restrict__ bi, unsigned short* __restrict__ hs,
    unsigned short* __restrict__ hfin)
{
    const int row = blockIdx.x, tid = threadIdx.x;
    const float* xr = x + (size_t)row * D_;
    float v0 = xr[tid], v1 = xr[tid + 256];
    float s1 = v0 + v1;
#pragma unroll
    for (int off = 32; off; off >>= 1) s1 += __shfl_down(s1, off, 64);
    __shared__ float red[8];
    __shared__ float stat[2];
    const int wid = tid >> 6, lane = tid & 63;
    if (lane == 0) red[wid] = s1;
    __syncthreads();
    if (tid == 0) stat[0] = (red[0] + red[1] + red[2] + red[3]) * (1.f / (float)D_);
    __syncthreads();
    const float mean = stat[0];
    const float d0 = v0 - mean, d1 = v1 - mean;
    float s2 = d0 * d0 + d1 * d1;
#pragma unroll
    for (int off = 32; off; off >>= 1) s2 += __shfl_down(s2, off, 64);
    if (lane == 0) red[wid] = s2;
    __syncthreads();
    if (tid == 0) stat[1] = (red[0] + red[1] + red[2] + red[3]) * (1.f / (float)D_);
    __syncthreads();
    const float rstd = rsqrtf(stat[1] + 1e-5f);
    const float o0 = d0 * rstd * sc[tid] + bi[tid];
    const float o1 = d1 * rstd * sc[tid + 256] + bi[tid + 256];
    unsigned short a, b, c;
    const size_t base = (size_t)row * D_ + tid;
    split3(o0, a, b, c);
    hs[base] = a; hs[base + HSPLANE] = b; hs[base + 2 * HSPLANE] = c;
    if (FIN) hfin[base] = a;
    split3(o1, a, b, c);
    hs[base + 256] = a; hs[base + 256 + HSPLANE] = b; hs[base + 256 + 2 * HSPLANE] = c;
    if (FIN) hfin[base + 256] = a;
}

// ---------------------------------------------------------------- gemm128f: BN=128 (2x MFMA per A-byte vs gemm64f; L2-BW relief)
// A pre-split direct-global (3 planes); B staged from f32 with in-kernel split3 (bit-identical values).
// block 128x128, 4 waves of 64x64, XCD swizzle (nwg%8==0). KD=512.
// MODE: 0 = f32 store+bias; 2 = gelu->split3 planes
template<int MODE>
__global__ __launch_bounds__(256, 2) void gemm128f(const unsigned short* __restrict__ A3, size_t aplane,
    const float* __restrict__ Bf, int ldb, const float* __restrict__ bias,
    void* __restrict__ Cv, size_t cplane, int Nc, int ldc)
{
    constexpr int KD = 512;
    __shared__ __align__(16) unsigned short Bs[3][128][40];
    const int tid = threadIdx.x;
    const int gx = gridDim.x;
    const int nwg = gx * gridDim.y;
    const int bid = blockIdx.y * gx + blockIdx.x;
    const int cpx = nwg >> 3;
    const int swz = (bid & 7) * cpx + (bid >> 3);
    const int bm = (swz / gx) * 128, bn = (swz % gx) * 128;
    const int wid = tid >> 6, lane = tid & 63;
    const int wm = (wid >> 1) * 64, wn = (wid & 1) * 64;
    const int lr = lane & 15, lg = lane >> 4;
    const int scol = tid >> 1, skh = tid & 1;            // 128 cols; each thread covers 16 k's
    const int gcol = bn + scol;
    const unsigned short* Ap0 = A3 + (size_t)(bm + wm + lr) * KD + lg * 8;

    f32x4_t acc[4][4] = {};

#pragma unroll 4
    for (int k0 = 0; k0 < KD; k0 += 32) {
        unsigned short q0[16], q1[16], q2[16];
#pragma unroll
        for (int h = 0; h < 2; ++h) {
            float bv[8];
            if (gcol < Nc) {
#pragma unroll
                for (int j = 0; j < 8; ++j)
                    bv[j] = Bf[(size_t)(k0 + skh * 16 + h * 8 + j) * ldb + gcol];
            } else {
#pragma unroll
                for (int j = 0; j < 8; ++j) bv[j] = 0.f;
            }
#pragma unroll
            for (int j = 0; j < 8; ++j) split3(bv[j], q0[h * 8 + j], q1[h * 8 + j], q2[h * 8 + j]);
        }
        short8_t af[3][4];
#pragma unroll
        for (int m = 0; m < 4; ++m) {
            const unsigned short* ap = Ap0 + (size_t)m * 16 * KD + k0;
            af[0][m] = *(const short8_t*)ap;
            af[1][m] = *(const short8_t*)(ap + aplane);
            af[2][m] = *(const short8_t*)(ap + 2 * aplane);
        }
        __syncthreads();   // previous iteration's Bs reads complete
        *(uint4*)&Bs[0][scol][skh * 16]     = *(uint4*)&q0[0];
        *(uint4*)&Bs[0][scol][skh * 16 + 8] = *(uint4*)&q0[8];
        *(uint4*)&Bs[1][scol][skh * 16]     = *(uint4*)&q1[0];
        *(uint4*)&Bs[1][scol][skh * 16 + 8] = *(uint4*)&q1[8];
        *(uint4*)&Bs[2][scol][skh * 16]     = *(uint4*)&q2[0];
        *(uint4*)&Bs[2][scol][skh * 16 + 8] = *(uint4*)&q2[8];
        __syncthreads();
        short8_t bg0[4], bgx[4];
#pragma unroll
        for (int n2 = 0; n2 < 4; ++n2) bg0[n2] = *(const short8_t*)&Bs[0][wn + n2 * 16 + lr][lg * 8];
        // product order per output element identical to gemm64f: (a0b0,a0b1,a1b0,a1b1,a0b2,a2b0)
#pragma unroll
        for (int m = 0; m < 4; ++m)
#pragma unroll
            for (int n2 = 0; n2 < 4; ++n2) acc[m][n2] = MFMA16(af[0][m], bg0[n2], acc[m][n2]);
#pragma unroll
        for (int n2 = 0; n2 < 4; ++n2) bgx[n2] = *(const short8_t*)&Bs[1][wn + n2 * 16 + lr][lg * 8];
#pragma unroll
        for (int m = 0; m < 4; ++m)
#pragma unroll
            for (int n2 = 0; n2 < 4; ++n2) {
                f32x4_t c = acc[m][n2];
                c = MFMA16(af[0][m], bgx[n2], c);
                c = MFMA16(af[1][m], bg0[n2], c);
                c = MFMA16(af[1][m], bgx[n2], c);
                acc[m][n2] = c;
            }
#pragma unroll
        for (int n2 = 0; n2 < 4; ++n2) bgx[n2] = *(const short8_t*)&Bs[2][wn + n2 * 16 + lr][lg * 8];
#pragma unroll
        for (int m = 0; m < 4; ++m)
#pragma unroll
            for (int n2 = 0; n2 < 4; ++n2) {
                f32x4_t c = acc[m][n2];
                c = MFMA16(af[0][m], bgx[n2], c);
                c = MFMA16(af[2][m], bg0[n2], c);
                acc[m][n2] = c;
            }
    }
#pragma unroll
    for (int m = 0; m < 4; ++m)
#pragma unroll
        for (int n2 = 0; n2 < 4; ++n2) {
            const int col = bn + wn + n2 * 16 + lr;
            if (col >= Nc) continue;
            const float bv = bias ? bias[col] : 0.f;
            const int row0 = bm + wm + m * 16 + lg * 4;
#pragma unroll
            for (int r = 0; r < 4; ++r) {
                float v = acc[m][n2][r] + bv;
                if (MODE == 2) {
                    const float t = v;
                    v = 0.5f * t * (1.f + tanhf(0.7978845608028654f * (t + 0.044715f * t * t * t)));
                    unsigned short a, b, c;
                    split3(v, a, b, c);
                    unsigned short* Cp = (unsigned short*)Cv + (size_t)(row0 + r) * ldc + col;
                    Cp[0] = a; Cp[cplane] = b; Cp[2 * cplane] = c;
                } else {
                    ((float*)Cv)[(size_t)(row0 + r) * ldc + col] = v;
                }
            }
        }
}

// ---------------------------------------------------------------- gemm64f: BN=64 (for wo/W2 where BN=128 would underfill the grid)
// MODE: 1 = f32 += (KD=512); 4 = f32 += (KD=1024)
template<int MODE>
__global__ __launch_bounds__(256, 2) void gemm64f(const unsigned short* __restrict__ A3, size_t aplane,
    const float* __restrict__ Bf, int ldb, const float* __restrict__ bias,
    void* __restrict__ Cv, size_t cplane, int Nc, int ldc)
{
    constexpr int KD = (MODE == 4) ? 1024 : 512;
    __shared__ __align__(16) unsigned short Bs[3][64][40];
    const int tid = threadIdx.x;
    const int gx = gridDim.x;
    const int nwg = gx * gridDim.y;
    const int bid = blockIdx.y * gx + blockIdx.x;
    const int cpx = nwg >> 3;
    const int swz = (bid & 7) * cpx + (bid >> 3);
    const int bm = (swz / gx) * 128, bn = (swz % gx) * 64;
    const int wid = tid >> 6, lane = tid & 63;
    const int wm = (wid >> 1) * 64, wn = (wid & 1) * 32;
    const int lr = lane & 15, lg = lane >> 4;
    const int scol = tid >> 2, skq = tid & 3;
    const int gcol = bn + scol;
    const unsigned short* Ap0 = A3 + (size_t)(bm + wm + lr) * KD + lg * 8;

    f32x4_t acc[4][2] = {};

#pragma unroll
    for (int k0 = 0; k0 < KD; k0 += 32) {
        float bv[8];
        if (gcol < Nc) {
#pragma unroll
            for (int j = 0; j < 8; ++j) bv[j] = Bf[(size_t)(k0 + skq * 8 + j) * ldb + gcol];
        } else {
#pragma unroll
            for (int j = 0; j < 8; ++j) bv[j] = 0.f;
        }
        unsigned short q0[8], q1[8], q2[8];
#pragma unroll
        for (int j = 0; j < 8; ++j) split3(bv[j], q0[j], q1[j], q2[j]);
        short8_t af[3][4];
#pragma unroll
        for (int m = 0; m < 4; ++m) {
            const unsigned short* ap = Ap0 + (size_t)m * 16 * KD + k0;
            af[0][m] = *(const short8_t*)ap;
            af[1][m] = *(const short8_t*)(ap + aplane);
            af[2][m] = *(const short8_t*)(ap + 2 * aplane);
        }
        __syncthreads();
        *(uint4*)&Bs[0][scol][skq * 8] = *(uint4*)&q0[0];
        *(uint4*)&Bs[1][scol][skq * 8] = *(uint4*)&q1[0];
        *(uint4*)&Bs[2][scol][skq * 8] = *(uint4*)&q2[0];
        __syncthreads();
        short8_t bg[3][2];
#pragma unroll
        for (int s = 0; s < 3; ++s)
#pragma unroll
            for (int n2 = 0; n2 < 2; ++n2)
                bg[s][n2] = *(const short8_t*)&Bs[s][wn + n2 * 16 + lr][lg * 8];
#pragma unroll
        for (int m = 0; m < 4; ++m)
#pragma unroll
            for (int n2 = 0; n2 < 2; ++n2) {
                f32x4_t c = acc[m][n2];
                c = MFMA16(af[0][m], bg[0][n2], c);
                c = MFMA16(af[0][m], bg[1][n2], c);
                c = MFMA16(af[1][m], bg[0][n2], c);
                c = MFMA16(af[1][m], bg[1][n2], c);
                c = MFMA16(af[0][m], bg[2][n2], c);
                c = MFMA16(af[2][m], bg[0][n2], c);
                acc[m][n2] = c;
            }
    }
#pragma unroll
    for (int m = 0; m < 4; ++m)
#pragma unroll
        for (int n2 = 0; n2 < 2; ++n2) {
            const int col = bn + wn + n2 * 16 + lr;
            if (col >= Nc) continue;
            const float bv = bias ? bias[col] : 0.f;
            const int row0 = bm + wm + m * 16 + lg * 4;
#pragma unroll
            for (int r = 0; r < 4; ++r) {
                float* cp = (float*)Cv + (size_t)(row0 + r) * ldc + col;
                *cp = *cp + acc[m][n2][r] + bv;
            }
        }
}

// ---------------------------------------------------------------- masked classifier re-run (bf16 single product; W f32 in-kernel cast)
__global__ __launch_bounds__(256) void rerun_kernel(const unsigned short* __restrict__ A,
    const float* __restrict__ Wc, const float* __restrict__ bias,
    const int* __restrict__ chosen, const int kk, float* __restrict__ out)
{
    __shared__ int anyrow;
    const int tid = threadIdx.x;
    const int bm = blockIdx.y * 128, bn = blockIdx.x * 64;
    if (tid == 0) anyrow = 0;
    __syncthreads();
    if (tid < 128 && chosen[bm + tid] == kk) anyrow = 1;
    __syncthreads();
    if (!anyrow) return;
    const int wid = tid >> 6, lane = tid & 63;
    const int wm = (wid >> 1) * 64, wn = (wid & 1) * 32;
    const int lr = lane & 15, lg = lane >> 4;
    f32x4_t acc[4][2] = {};
#pragma unroll
    for (int k0 = 0; k0 < D_; k0 += 32) {
        short8_t af[4], bg[2];
#pragma unroll
        for (int m = 0; m < 4; ++m)
            af[m] = *(const short8_t*)(A + (size_t)(bm + wm + m * 16 + lr) * D_ + k0 + lg * 8);
#pragma unroll
        for (int n2 = 0; n2 < 2; ++n2) {
            const int col = bn + wn + n2 * 16 + lr;
            if (col < C_) {
#pragma unroll
                for (int j = 0; j < 8; ++j)
                    bg[n2][j] = (short)f2bf(Wc[(size_t)(k0 + lg * 8 + j) * C_ + col]);
            } else {
#pragma unroll
                for (int j = 0; j < 8; ++j) bg[n2][j] = 0;
            }
        }
#pragma unroll
        for (int m = 0; m < 4; ++m)
#pragma unroll
            for (int n2 = 0; n2 < 2; ++n2)
                acc[m][n2] = MFMA16(af[m], bg[n2], acc[m][n2]);
    }
#pragma unroll
    for (int m = 0; m < 4; ++m)
#pragma unroll
        for (int n2 = 0; n2 < 2; ++n2) {
            const int col = bn + wn + n2 * 16 + lr;
            if (col >= C_) continue;
            const float bv = bias[col];
            const int row0 = bm + wm + m * 16 + lg * 4;
#pragma unroll
            for (int r = 0; r < 4; ++r) {
                const int row = row0 + r;
                if (chosen[row] == kk) out[(size_t)row * C_ + col] = acc[m][n2][r] + bv;
            }
        }
}

// ---------------------------------------------------------------- MFMA flash attention (bf16x3 split in-kernel), split-bf16 output
__global__ __launch_bounds__(256) void attn_mfma_kernel(const float* __restrict__ qkv, unsigned short* __restrict__ hsO)
{
    __shared__ __align__(16) unsigned short Ks[3][32][72];
    __shared__ __align__(16) unsigned short Vt[3][64][40];
    __shared__ __align__(16) unsigned short Ps[4][3][16][40];
    const int qt = blockIdx.x, hh = blockIdx.y, n = blockIdx.z;
    const int tid = threadIdx.x;
    const int w = tid >> 6, lane = tid & 63;
    const int lr = lane & 15, lg = lane >> 4;
    const size_t rs = 3 * D_;
    const float* base = qkv + (size_t)n * S_ * rs + hh * DH_;

    short8_t qf[3][2];
    {
        const int qrow = qt * 64 + w * 16 + lr;
#pragma unroll
        for (int ks = 0; ks < 2; ++ks) {
            const float* qp = base + (size_t)qrow * rs + ks * 32 + lg * 8;
            float v[8];
            *(float4*)&v[0] = ((const float4*)qp)[0];
            *(float4*)&v[4] = ((const float4*)qp)[1];
#pragma unroll
            for (int j = 0; j < 8; ++j) {
                unsigned short a, b, c;
                split3(v[j], a, b, c);
                qf[0][ks][j] = (short)a; qf[1][ks][j] = (short)b; qf[2][ks][j] = (short)c;
            }
        }
    }

    f32x4_t oacc[4] = {};
    float m_r[4], l_r[4];
#pragma unroll
    for (int r = 0; r < 4; ++r) { m_r[r] = -1e30f; l_r[r] = 0.f; }

    const int ktmax = 2 * qt + 2;
    for (int kt = 0; kt < ktmax; ++kt) {
        __syncthreads();
        {
            const int key = tid & 31, seg = tid >> 5;
            const float* kp = base + (size_t)(kt * 32 + key) * rs + D_ + seg * 8;
            const float* vp = kp + D_;
            float kv[8], vv[8];
            *(float4*)&kv[0] = ((const float4*)kp)[0];
            *(float4*)&kv[4] = ((const float4*)kp)[1];
            *(float4*)&vv[0] = ((const float4*)vp)[0];
            *(float4*)&vv[4] = ((const float4*)vp)[1];
            unsigned short k0a[8], k1a[8], k2a[8];
#pragma unroll
            for (int j = 0; j < 8; ++j) split3(kv[j], k0a[j], k1a[j], k2a[j]);
            *(uint4*)&Ks[0][key][seg * 8] = *(uint4*)&k0a[0];
            *(uint4*)&Ks[1][key][seg * 8] = *(uint4*)&k1a[0];
            *(uint4*)&Ks[2][key][seg * 8] = *(uint4*)&k2a[0];
#pragma unroll
            for (int j = 0; j < 8; ++j) {
                unsigned short a, b, c;
                split3(vv[j], a, b, c);
                Vt[0][seg * 8 + j][key] = a;
                Vt[1][seg * 8 + j][key] = b;
                Vt[2][seg * 8 + j][key] = c;
            }
        }
        __syncthreads();
        f32x4_t sacc[2] = {};
#pragma unroll
        for (int n2 = 0; n2 < 2; ++n2) {
#pragma unroll
            for (int ks = 0; ks < 2; ++ks) {
                short8_t kb0 = *(const short8_t*)&Ks[0][n2 * 16 + lr][ks * 32 + lg * 8];
                short8_t kb1 = *(const short8_t*)&Ks[1][n2 * 16 + lr][ks * 32 + lg * 8];
                short8_t kb2 = *(const short8_t*)&Ks[2][n2 * 16 + lr][ks * 32 + lg * 8];
                f32x4_t c = sacc[n2];
                c = MFMA16(qf[0][ks], kb0, c);
                c = MFMA16(qf[0][ks], kb1, c);
                c = MFMA16(qf[1][ks], kb0, c);
                c = MFMA16(qf[1][ks], kb1, c);
                c = MFMA16(qf[0][ks], kb2, c);
                c = MFMA16(qf[2][ks], kb0, c);
                sacc[n2] = c;
            }
        }
        float p[2][4];
#pragma unroll
        for (int n2 = 0; n2 < 2; ++n2)
#pragma unroll
            for (int r = 0; r < 4; ++r) {
                float s = sacc[n2][r] * 0.125f;
                const int key = kt * 32 + n2 * 16 + lr;
                const int qrow = qt * 64 + w * 16 + lg * 4 + r;
                if (key > qrow) s = -1e30f;
                p[n2][r] = s;
            }
        float scl[4];
#pragma unroll
        for (int r = 0; r < 4; ++r) {
            float tm = fmaxf(p[0][r], p[1][r]);
            tm = fmaxf(tm, __shfl_xor(tm, 1));
            tm = fmaxf(tm, __shfl_xor(tm, 2));
            tm = fmaxf(tm, __shfl_xor(tm, 4));
            tm = fmaxf(tm, __shfl_xor(tm, 8));
            const float mnew = fmaxf(m_r[r], tm);
            scl[r] = expf(m_r[r] - mnew);
            m_r[r] = mnew;
        }
#pragma unroll
        for (int r = 0; r < 4; ++r) {
            p[0][r] = expf(p[0][r] - m_r[r]);
            p[1][r] = expf(p[1][r] - m_r[r]);
            float ts = p[0][r] + p[1][r];
            ts += __shfl_xor(ts, 1);
            ts += __shfl_xor(ts, 2);
            ts += __shfl_xor(ts, 4);
            ts += __shfl_xor(ts, 8);
            l_r[r] = l_r[r] * scl[r] + ts;
        }
#pragma unroll
        for (int nf = 0; nf < 4; ++nf)
#pragma unroll
            for (int r = 0; r < 4; ++r) oacc[nf][r] *= scl[r];
#pragma unroll
        for (int n2 = 0; n2 < 2; ++n2)
#pragma unroll
            for (int r = 0; r < 4; ++r) {
                unsigned short a, b, c;
                split3(p[n2][r], a, b, c);
                Ps[w][0][lg * 4 + r][n2 * 16 + lr] = a;
                Ps[w][1][lg * 4 + r][n2 * 16 + lr] = b;
                Ps[w][2][lg * 4 + r][n2 * 16 + lr] = c;
            }
        short8_t pa0 = *(const short8_t*)&Ps[w][0][lr][lg * 8];
        short8_t pa1 = *(const short8_t*)&Ps[w][1][lr][lg * 8];
        short8_t pa2 = *(const short8_t*)&Ps[w][2][lr][lg * 8];
#pragma unroll
        for (int nf = 0; nf < 4; ++nf) {
            short8_t vb0 = *(const short8_t*)&Vt[0][nf * 16 + lr][lg * 8];
            short8_t vb1 = *(const short8_t*)&Vt[1][nf * 16 + lr][lg * 8];
            short8_t vb2 = *(const short8_t*)&Vt[2][nf * 16 + lr][lg * 8];
            f32x4_t c = oacc[nf];
            c = MFMA16(pa0, vb0, c);
            c = MFMA16(pa0, vb1, c);
            c = MFMA16(pa1, vb0, c);
            c = MFMA16(pa1, vb1, c);
            c = MFMA16(pa0, vb2, c);
            c = MFMA16(pa2, vb0, c);
            oacc[nf] = c;
        }
    }
    float inv[4];
#pragma unroll
    for (int r = 0; r < 4; ++r) inv[r] = 1.f / l_r[r];
#pragma unroll
    for (int nf = 0; nf < 4; ++nf)
#pragma unroll
        for (int r = 0; r < 4; ++r) {
            const int qrow = qt * 64 + w * 16 + lg * 4 + r;
            const size_t idx = ((size_t)n * S_ + qrow) * D_ + hh * DH_ + nf * 16 + lr;
            unsigned short a, b, c;
            split3(oacc[nf][r] * inv[r], a, b, c);
            hsO[idx] = a; hsO[idx + HSPLANE] = b; hsO[idx + 2 * HSPLANE] = c;
        }
}

// ---------------------------------------------------------------- confidence head (reads split planes 0+1)
__global__ __launch_bounds__(256) void conf_kernel(const unsigned short* __restrict__ hs,
    const float* __restrict__ w, const float* __restrict__ bc, float* __restrict__ conf_out, int k)
{
    const int wid = threadIdx.x >> 6, lane = threadIdx.x & 63;
    const int row = blockIdx.x * 4 + wid;
    const unsigned short* h0 = hs + (size_t)row * D_;
    const unsigned short* h1 = h0 + HSPLANE;
    float sm = 0.f;
#pragma unroll
    for (int j = 0; j < 8; ++j) {
        const int i = lane + 64 * j;
        sm += (b2f(h0[i]) + b2f(h1[i])) * w[i];
    }
#pragma unroll
    for (int off = 32; off; off >>= 1) sm += __shfl_down(sm, off, 64);
    if (lane == 0) {
        const int n = row >> 10, s = row & (S_ - 1);
        conf_out[((size_t)n * K_ + k) * S_ + s] = sm + bc[0];
    }
}

// ---------------------------------------------------------------- per-token CE loss
__global__ __launch_bounds__(256) void loss_kernel(const float* __restrict__ logits,
    const int* __restrict__ y, float* __restrict__ loss)
{
    const int row = blockIdx.x;
    const float* lr = logits + (size_t)row * C_;
    const int tid = threadIdx.x;
    __shared__ float red[256];
    float mx = -1e30f;
    for (int c = tid; c < C_; c += 256) mx = fmaxf(mx, lr[c]);
    red[tid] = mx; __syncthreads();
    for (int st = 128; st > 0; st >>= 1) {
        if (tid < st) red[tid] = fmaxf(red[tid], red[tid + st]);
        __syncthreads();
    }
    mx = red[0];
    __syncthreads();
    float sm = 0.f;
    for (int c = tid; c < C_; c += 256) sm += expf(lr[c] - mx);
    red[tid] = sm; __syncthreads();
    for (int st = 128; st > 0; st >>= 1) {
        if (tid < st) red[tid] += red[tid + st];
        __syncthreads();
    }
    if (tid == 0) loss[row] = logf(red[0]) + mx - lr[y[row]];
}

// ---------------------------------------------------------------- capacity auction: LDS-staged, pre-sorted
__global__ __launch_bounds__(256) void routing_kernel(const float* __restrict__ loss,
    float* __restrict__ idx_out, int* __restrict__ chosen_buf)
{
    __shared__ float l_s[K_][S_];
    __shared__ unsigned char ord_s[S_];
    const int n = blockIdx.x;
    const int tid = threadIdx.x;
#pragma unroll
    for (int k = 0; k < K_; ++k)
        ((float4*)l_s[k])[tid] = ((const float4*)(loss + (size_t)k * M_ + n * S_))[tid];
    __syncthreads();
    for (int s = tid; s < S_; s += 256) {
        float l[K_];
#pragma unroll
        for (int k = 0; k < K_; ++k) l[k] = l_s[k][s];
        int ord[K_] = {0, 1, 2, 3};
#pragma unroll
        for (int i = 1; i < K_; ++i) {
            const int v = ord[i];
            int j = i;
            while (j > 0 && l[ord[j - 1]] > l[v]) { ord[j] = ord[j - 1]; --j; }
            ord[j] = v;
        }
        ord_s[s] = (unsigned char)(ord[0] | (ord[1] << 2) | (ord[2] << 4) | (ord[3] << 6));
    }
    __syncthreads();
    if (tid == 0) {
        int tc[K_] = {0, 0, 0, 0};
        for (int s = 0; s < S_; ++s) {
            const unsigned b = ord_s[s];
            int ch = b & 3;
#pragma unroll
            for (int j = 0; j < K_; ++j) {
                const int m = (b >> (2 * j)) & 3;
                if (tc[m] < CAP_) { ch = m; break; }
            }
            ++tc[ch];
            chosen_buf[n * S_ + s] = ch;
            idx_out[n * S_ + s] = (float)ch;
        }
    }
}

// ----------------------------------------------------------------
extern "C" void kernel_launch(void* const* d_in, const int* in_sizes, int n_in,
                              void* d_out, int out_size, void* d_ws, size_t ws_size,
                              hipStream_t stream)
{
    const int*   x_in = (const int*)d_in[0];
    const int*   y    = (const int*)d_in[1];
    const float* tok  = (const float*)d_in[2];
    const float* pos  = (const float*)d_in[3];
    const float* ln1s = (const float*)d_in[4];
    const float* ln1b = (const float*)d_in[5];
    const float* Wqkv = (const float*)d_in[6];
    const float* bqkv = (const float*)d_in[7];
    const float* Wo   = (const float*)d_in[8];
    const float* bo   = (const float*)d_in[9];
    const float* ln2s = (const float*)d_in[10];
    const float* ln2b = (const float*)d_in[11];
    const float* W1   = (const float*)d_in[12];
    const float* b1   = (const float*)d_in[13];
    const float* W2   = (const float*)d_in[14];
    const float* b2   = (const float*)d_in[15];
    const float* lnfs = (const float*)d_in[16];
    const float* lnfb = (const float*)d_in[17];
    const float* Wcls = (const float*)d_in[18];
    const float* bcls = (const float*)d_in[19];
    const float* Wcnf = (const float*)d_in[20];
    const float* bcnf = (const float*)d_in[21];

    // ws layout (same as passing round-13):
    // R [M][1536] f32 (qkv f32 | mids bf16x3 [3][M][1024] | logits f32 [M][1000])
    // hs [3][M][512]bf16 | x [M][512]f32 | hfin [K][M][512]bf16 | (reserved) | loss [K][M]f32 | chosen [M]i32
    if (ws_size < 66142208) return;   // fail fast instead of corrupting
    float* R = (float*)d_ws;
    unsigned short* hs   = (unsigned short*)(R + (size_t)M_ * 1536);
    float* x             = (float*)(hs + 3 * HSPLANE);
    unsigned short* hfin = (unsigned short*)(x + (size_t)M_ * D_);
    unsigned short* Wt   = hfin + (size_t)K_ * M_ * D_;   // reserved (unused)
    float* loss          = (float*)(Wt + 3 * (size_t)524288);
    int*   chosen        = (int*)(loss + (size_t)K_ * M_);
    unsigned short* mids = (unsigned short*)R;            // mlp mid split planes (qkv dead then)
    const size_t midplane = (size_t)M_ * 1024;

    float* out      = (float*)d_out;                     // [N][S][C]
    float* conf_out = out + (size_t)M_ * C_;             // [N][K][S]
    float* idx_out  = conf_out + (size_t)N_ * K_ * S_;   // [N][S]

    for (int k = 0; k < K_; ++k) {
        embed_kernel<<<(M_ * (D_ / 4) + 255) / 256, 256, 0, stream>>>(
            x_in, tok + (size_t)k * V_ * D_, pos + (size_t)k * S_ * D_, x);
        for (int i = 0; i < NB_; ++i) {
            const size_t ki = (size_t)k * NB_ + i;
            ln_kernel<0><<<M_, 256, 0, stream>>>(x, ln1s + ki * D_, ln1b + ki * D_, hs, nullptr);
            gemm128f<0><<<dim3(12, 32), 256, 0, stream>>>(
                hs, HSPLANE, Wqkv + ki * D_ * 3 * D_, 3 * D_, bqkv + ki * 3 * D_,
                R, 0, 3 * D_, 3 * D_);
            attn_mfma_kernel<<<dim3(S_ / 64, NH_, N_), 256, 0, stream>>>(R, hs);
            gemm64f<1><<<dim3(8, 32), 256, 0, stream>>>(
                hs, HSPLANE, Wo + ki * D_ * D_, D_, bo + ki * D_, x, 0, D_, D_);
            ln_kernel<0><<<M_, 256, 0, stream>>>(x, ln2s + ki * D_, ln2b + ki * D_, hs, nullptr);
            for (int c = 0; c < 2; ++c) {   // MLP over two 1024-col mid chunks (mids in R; qkv dead)
                gemm128f<2><<<dim3(8, 32), 256, 0, stream>>>(
                    hs, HSPLANE, W1 + ki * D_ * HD_ + c * 1024, HD_, b1 + ki * HD_ + c * 1024,
                    mids, midplane, 1024, 1024);
                gemm64f<4><<<dim3(8, 32), 256, 0, stream>>>(
                    mids, midplane, W2 + ki * HD_ * D_ + (size_t)c * 1024 * D_, D_,
                    (c == 0) ? (b2 + ki * D_) : nullptr, x, 0, D_, D_);
            }
        }
        ln_kernel<1><<<M_, 256, 0, stream>>>(x, lnfs + (size_t)k * D_, lnfb + (size_t)k * D_,
                                             hs, hfin + (size_t)k * M_ * D_);
        gemm128f<0><<<dim3(8, 32), 256, 0, stream>>>(
            hs, HSPLANE, Wcls + (size_t)k * D_ * C_, C_, bcls + (size_t)k * C_, R, 0, C_, C_);
        conf_kernel<<<M_ / 4, 256, 0, stream>>>(hs, Wcnf + (size_t)k * D_, bcnf + k, conf_out, k);
        loss_kernel<<<M_, 256, 0, stream>>>(R, y, loss + (size_t)k * M_);
    }
    routing_kernel<<<N_, 256, 0, stream>>>(loss, idx_out, chosen);
    for (int k = 0; k < K_; ++k)
        rerun_kernel<<<dim3(16, 32), 256, 0, stream>>>(
            hfin + (size_t)k * M_ * D_, Wcls + (size_t)k * D_ * C_, bcls + (size_t)k * C_,
            chosen, k, out);
}

// Round 15
// 13595.972 us; speedup vs baseline: 1.3070x; 1.3070x over previous
//
#include <hip/hip_runtime.h>
#include <hip/hip_bf16.h>

#define N_  4
#define S_  1024
#define K_  4
#define V_  32000
#define C_  1000
#define D_  512
#define NH_ 8
#define NB_ 6
#define HD_ 2048
#define DH_ 64
#define CAP_ 256
#define M_  (N_*S_)   // 4096 rows

typedef __attribute__((ext_vector_type(8))) short short8_t;   // 8 bf16 = 4 VGPR
typedef __attribute__((ext_vector_type(4))) float f32x4_t;

#define MFMA16(a,b,c) __builtin_amdgcn_mfma_f32_16x16x32_bf16((a),(b),(c),0,0,0)

#define HSPLANE ((size_t)M_ * D_)        // elems per split plane of hs

static __device__ __forceinline__ float bfround(float v) {   // RNE to bf16, as float
    unsigned u = __float_as_uint(v);
    u = (u + 0x7FFFu + ((u >> 16) & 1u)) & 0xFFFF0000u;
    return __uint_as_float(u);
}
static __device__ __forceinline__ void split3(float v, unsigned short& a, unsigned short& b, unsigned short& c) {
    const float f0 = bfround(v);      const float r1 = v - f0;
    const float f1 = bfround(r1);     const float f2 = bfround(r1 - f1);
    a = (unsigned short)(__float_as_uint(f0) >> 16);
    b = (unsigned short)(__float_as_uint(f1) >> 16);
    c = (unsigned short)(__float_as_uint(f2) >> 16);
}
static __device__ __forceinline__ unsigned short f2bf(float f) {
    unsigned u = __float_as_uint(f);
    return (unsigned short)((u + 0x7FFFu + ((u >> 16) & 1u)) >> 16);
}
static __device__ __forceinline__ float b2f(unsigned short u) {
    return __uint_as_float((unsigned)u << 16);
}

// ---------------------------------------------------------------- embed
__global__ __launch_bounds__(256) void embed_kernel(const int* __restrict__ x_in,
    const float* __restrict__ tok, const float* __restrict__ pos, float* __restrict__ x)
{
    const int idx = blockIdx.x * 256 + threadIdx.x;
    const int total = M_ * (D_ / 4);
    if (idx >= total) return;
    const int d = (idx & (D_ / 4 - 1)) * 4;
    const int row = idx >> 7;
    const int s = row & (S_ - 1);
    const int t = x_in[row];
    const float4 a = *(const float4*)(tok + (size_t)t * D_ + d);
    const float4 b = *(const float4*)(pos + (size_t)s * D_ + d);
    float4 r; r.x = a.x + b.x; r.y = a.y + b.y; r.z = a.z + b.z; r.w = a.w + b.w;
    *(float4*)(x + (size_t)row * D_ + d) = r;
}

// ---------------------------------------------------------------- layernorm -> split bf16x3 planes (FIN: also write hfin plane0)
template<int FIN>
__global__ __launch_bounds__(256) void ln_kernel(const float* __restrict__ x,
    const float* __restrict__ sc, const float* __restrict__ bi, unsigned short* __restrict__ hs,
    unsigned short* __restrict__ hfin)
{
    const int row = blockIdx.x, tid = threadIdx.x;
    const float* xr = x + (size_t)row * D_;
    float v0 = xr[tid], v1 = xr[tid + 256];
    float s1 = v0 + v1;
#pragma unroll
    for (int off = 32; off; off >>= 1) s1 += __shfl_down(s1, off, 64);
    __shared__ float red[8];
    __shared__ float stat[2];
    const int wid = tid >> 6, lane = tid & 63;
    if (lane == 0) red[wid] = s1;
    __syncthreads();
    if (tid == 0) stat[0] = (red[0] + red[1] + red[2] + red[3]) * (1.f / (float)D_);
    __syncthreads();
    const float mean = stat[0];
    const float d0 = v0 - mean, d1 = v1 - mean;
    float s2 = d0 * d0 + d1 * d1;
#pragma unroll
    for (int off = 32; off; off >>= 1) s2 += __shfl_down(s2, off, 64);
    if (lane == 0) red[wid] = s2;
    __syncthreads();
    if (tid == 0) stat[1] = (red[0] + red[1] + red[2] + red[3]) * (1.f / (float)D_);
    __syncthreads();
    const float rstd = rsqrtf(stat[1] + 1e-5f);
    const float o0 = d0 * rstd * sc[tid] + bi[tid];
    const float o1 = d1 * rstd * sc[tid + 256] + bi[tid + 256];
    unsigned short a, b, c;
    const size_t base = (size_t)row * D_ + tid;
    split3(o0, a, b, c);
    hs[base] = a; hs[base + HSPLANE] = b; hs[base + 2 * HSPLANE] = c;
    if (FIN) hfin[base] = a;
    split3(o1, a, b, c);
    hs[base + 256] = a; hs[base + 256 + HSPLANE] = b; hs[base + 256 + 2 * HSPLANE] = c;
    if (FIN) hfin[base + 256] = a;
}

// ---------------------------------------------------------------- fp32-accurate GEMM via bf16x3: A pre-split direct-global,
// B staged from f32 weights with in-kernel split3. block 128x64, 4 waves of 64x32, XCD swizzle (nwg%8==0).
// MODE: 0 = f32 store+bias (KD=512); 1 = f32 += (KD=512); 2 = gelu->split3 planes (KD=512); 4 = f32 += (KD=1024)
template<int MODE>
__global__ __launch_bounds__(256, 2) void gemm64f(const unsigned short* __restrict__ A3, size_t aplane,
    const float* __restrict__ Bf, int ldb, const float* __restrict__ bias,
    void* __restrict__ Cv, size_t cplane, int Nc, int ldc)
{
    constexpr int KD = (MODE == 4) ? 1024 : 512;
    __shared__ __align__(16) unsigned short Bs[3][64][40];
    const int tid = threadIdx.x;
    const int gx = gridDim.x;
    const int nwg = gx * gridDim.y;
    const int bid = blockIdx.y * gx + blockIdx.x;
    const int cpx = nwg >> 3;
    const int swz = (bid & 7) * cpx + (bid >> 3);
    const int bm = (swz / gx) * 128, bn = (swz % gx) * 64;
    const int wid = tid >> 6, lane = tid & 63;
    const int wm = (wid >> 1) * 64, wn = (wid & 1) * 32;
    const int lr = lane & 15, lg = lane >> 4;
    const int scol = tid >> 2, skq = tid & 3;            // B staging: 2-way-free bank pattern
    const int gcol = bn + scol;
    const unsigned short* Ap0 = A3 + (size_t)(bm + wm + lr) * KD + lg * 8;

    f32x4_t acc[4][2] = {};

#pragma unroll
    for (int k0 = 0; k0 < KD; k0 += 32) {
        float bv[8];
        if (gcol < Nc) {
#pragma unroll
            for (int j = 0; j < 8; ++j) bv[j] = Bf[(size_t)(k0 + skq * 8 + j) * ldb + gcol];
        } else {
#pragma unroll
            for (int j = 0; j < 8; ++j) bv[j] = 0.f;
        }
        unsigned short q0[8], q1[8], q2[8];
#pragma unroll
        for (int j = 0; j < 8; ++j) split3(bv[j], q0[j], q1[j], q2[j]);
        short8_t af[3][4];
#pragma unroll
        for (int m = 0; m < 4; ++m) {
            const unsigned short* ap = Ap0 + (size_t)m * 16 * KD + k0;
            af[0][m] = *(const short8_t*)ap;
            af[1][m] = *(const short8_t*)(ap + aplane);
            af[2][m] = *(const short8_t*)(ap + 2 * aplane);
        }
        __syncthreads();   // previous iteration's Bs reads complete
        *(uint4*)&Bs[0][scol][skq * 8] = *(uint4*)&q0[0];
        *(uint4*)&Bs[1][scol][skq * 8] = *(uint4*)&q1[0];
        *(uint4*)&Bs[2][scol][skq * 8] = *(uint4*)&q2[0];
        __syncthreads();
        short8_t bg[3][2];
#pragma unroll
        for (int s = 0; s < 3; ++s)
#pragma unroll
            for (int n2 = 0; n2 < 2; ++n2)
                bg[s][n2] = *(const short8_t*)&Bs[s][wn + n2 * 16 + lr][lg * 8];
#pragma unroll
        for (int m = 0; m < 4; ++m)
#pragma unroll
            for (int n2 = 0; n2 < 2; ++n2) {
                f32x4_t c = acc[m][n2];
                c = MFMA16(af[0][m], bg[0][n2], c);
                c = MFMA16(af[0][m], bg[1][n2], c);
                c = MFMA16(af[1][m], bg[0][n2], c);
                c = MFMA16(af[1][m], bg[1][n2], c);
                c = MFMA16(af[0][m], bg[2][n2], c);
                c = MFMA16(af[2][m], bg[0][n2], c);
                acc[m][n2] = c;
            }
    }
#pragma unroll
    for (int m = 0; m < 4; ++m)
#pragma unroll
        for (int n2 = 0; n2 < 2; ++n2) {
            const int col = bn + wn + n2 * 16 + lr;
            if (col >= Nc) continue;
            const float bv = bias ? bias[col] : 0.f;
            const int row0 = bm + wm + m * 16 + lg * 4;
#pragma unroll
            for (int r = 0; r < 4; ++r) {
                float v = acc[m][n2][r] + bv;
                if (MODE == 2) {
                    const float t = v;
                    v = 0.5f * t * (1.f + tanhf(0.7978845608028654f * (t + 0.044715f * t * t * t)));
                    unsigned short a, b, c;
                    split3(v, a, b, c);
                    unsigned short* Cp = (unsigned short*)Cv + (size_t)(row0 + r) * ldc + col;
                    Cp[0] = a; Cp[cplane] = b; Cp[2 * cplane] = c;
                } else {
                    float* cp = (float*)Cv + (size_t)(row0 + r) * ldc + col;
                    if (MODE == 1 || MODE == 4) v += *cp;
                    *cp = v;
                }
            }
        }
}

// ---------------------------------------------------------------- masked classifier re-run (bf16 single product; W f32 in-kernel cast)
__global__ __launch_bounds__(256) void rerun_kernel(const unsigned short* __restrict__ A,
    const float* __restrict__ Wc, const float* __restrict__ bias,
    const int* __restrict__ chosen, const int kk, float* __restrict__ out)
{
    __shared__ int anyrow;
    const int tid = threadIdx.x;
    const int bm = blockIdx.y * 128, bn = blockIdx.x * 64;
    if (tid == 0) anyrow = 0;
    __syncthreads();
    if (tid < 128 && chosen[bm + tid] == kk) anyrow = 1;
    __syncthreads();
    if (!anyrow) return;
    const int wid = tid >> 6, lane = tid & 63;
    const int wm = (wid >> 1) * 64, wn = (wid & 1) * 32;
    const int lr = lane & 15, lg = lane >> 4;
    f32x4_t acc[4][2] = {};
#pragma unroll
    for (int k0 = 0; k0 < D_; k0 += 32) {
        short8_t af[4], bg[2];
#pragma unroll
        for (int m = 0; m < 4; ++m)
            af[m] = *(const short8_t*)(A + (size_t)(bm + wm + m * 16 + lr) * D_ + k0 + lg * 8);
#pragma unroll
        for (int n2 = 0; n2 < 2; ++n2) {
            const int col = bn + wn + n2 * 16 + lr;
            if (col < C_) {
#pragma unroll
                for (int j = 0; j < 8; ++j)
                    bg[n2][j] = (short)f2bf(Wc[(size_t)(k0 + lg * 8 + j) * C_ + col]);
            } else {
#pragma unroll
                for (int j = 0; j < 8; ++j) bg[n2][j] = 0;
            }
        }
#pragma unroll
        for (int m = 0; m < 4; ++m)
#pragma unroll
            for (int n2 = 0; n2 < 2; ++n2)
                acc[m][n2] = MFMA16(af[m], bg[n2], acc[m][n2]);
    }
#pragma unroll
    for (int m = 0; m < 4; ++m)
#pragma unroll
        for (int n2 = 0; n2 < 2; ++n2) {
            const int col = bn + wn + n2 * 16 + lr;
            if (col >= C_) continue;
            const float bv = bias[col];
            const int row0 = bm + wm + m * 16 + lg * 4;
#pragma unroll
            for (int r = 0; r < 4; ++r) {
                const int row = row0 + r;
                if (chosen[row] == kk) out[(size_t)row * C_ + col] = acc[m][n2][r] + bv;
            }
        }
}

// ---------------------------------------------------------------- MFMA flash attention (bf16x3 split in-kernel), split-bf16 output
// Round-15: reverse-qt launch order (big causal blocks first); Ks d-block XOR swizzle (4-way -> <=2-way staging).
__global__ __launch_bounds__(256) void attn_mfma_kernel(const float* __restrict__ qkv, unsigned short* __restrict__ hsO)
{
    __shared__ __align__(16) unsigned short Ks[3][32][72];
    __shared__ __align__(16) unsigned short Vt[3][64][40];
    __shared__ __align__(16) unsigned short Ps[4][3][16][40];
    const int qt = gridDim.x - 1 - blockIdx.x;   // descending: qt=15 (32 tiles) launches first
    const int hh = blockIdx.y, n = blockIdx.z;
    const int tid = threadIdx.x;
    const int w = tid >> 6, lane = tid & 63;
    const int lr = lane & 15, lg = lane >> 4;
    const size_t rs = 3 * D_;
    const float* base = qkv + (size_t)n * S_ * rs + hh * DH_;

    short8_t qf[3][2];
    {
        const int qrow = qt * 64 + w * 16 + lr;
#pragma unroll
        for (int ks = 0; ks < 2; ++ks) {
            const float* qp = base + (size_t)qrow * rs + ks * 32 + lg * 8;
            float v[8];
            *(float4*)&v[0] = ((const float4*)qp)[0];
            *(float4*)&v[4] = ((const float4*)qp)[1];
#pragma unroll
            for (int j = 0; j < 8; ++j) {
                unsigned short a, b, c;
                split3(v[j], a, b, c);
                qf[0][ks][j] = (short)a; qf[1][ks][j] = (short)b; qf[2][ks][j] = (short)c;
            }
        }
    }

    f32x4_t oacc[4] = {};
    float m_r[4], l_r[4];
#pragma unroll
    for (int r = 0; r < 4; ++r) { m_r[r] = -1e30f; l_r[r] = 0.f; }

    const int ktmax = 2 * qt + 2;
    for (int kt = 0; kt < ktmax; ++kt) {
        __syncthreads();
        {
            const int key = tid & 31, seg = tid >> 5;
            const int kswz = ((key & 3) ^ ((key >> 3) & 3));   // d-block permutation per key
            const float* kp = base + (size_t)(kt * 32 + key) * rs + D_ + seg * 8;
            const float* vp = kp + D_;
            float kv[8], vv[8];
            *(float4*)&kv[0] = ((const float4*)kp)[0];
            *(float4*)&kv[4] = ((const float4*)kp)[1];
            *(float4*)&vv[0] = ((const float4*)vp)[0];
            *(float4*)&vv[4] = ((const float4*)vp)[1];
            unsigned short k0a[8], k1a[8], k2a[8];
#pragma unroll
            for (int j = 0; j < 8; ++j) split3(kv[j], k0a[j], k1a[j], k2a[j]);
            *(uint4*)&Ks[0][key][(seg ^ kswz) * 8] = *(uint4*)&k0a[0];
            *(uint4*)&Ks[1][key][(seg ^ kswz) * 8] = *(uint4*)&k1a[0];
            *(uint4*)&Ks[2][key][(seg ^ kswz) * 8] = *(uint4*)&k2a[0];
#pragma unroll
            for (int j = 0; j < 8; ++j) {
                unsigned short a, b, c;
                split3(vv[j], a, b, c);
                Vt[0][seg * 8 + j][key] = a;
                Vt[1][seg * 8 + j][key] = b;
                Vt[2][seg * 8 + j][key] = c;
            }
        }
        __syncthreads();
        f32x4_t sacc[2] = {};
#pragma unroll
        for (int n2 = 0; n2 < 2; ++n2) {
            const int rk = n2 * 16 + lr;                       // key row being read
            const int rswz = ((rk & 3) ^ ((rk >> 3) & 3));
#pragma unroll
            for (int ks = 0; ks < 2; ++ks) {
                const int boff = ((ks * 4 + lg) ^ rswz) * 8;   // swizzled d-block offset
                short8_t kb0 = *(const short8_t*)&Ks[0][rk][boff];
                short8_t kb1 = *(const short8_t*)&Ks[1][rk][boff];
                short8_t kb2 = *(const short8_t*)&Ks[2][rk][boff];
                f32x4_t c = sacc[n2];
                c = MFMA16(qf[0][ks], kb0, c);
                c = MFMA16(qf[0][ks], kb1, c);
                c = MFMA16(qf[1][ks], kb0, c);
                c = MFMA16(qf[1][ks], kb1, c);
                c = MFMA16(qf[0][ks], kb2, c);
                c = MFMA16(qf[2][ks], kb0, c);
                sacc[n2] = c;
            }
        }
        float p[2][4];
#pragma unroll
        for (int n2 = 0; n2 < 2; ++n2)
#pragma unroll
            for (int r = 0; r < 4; ++r) {
                float s = sacc[n2][r] * 0.125f;
                const int key = kt * 32 + n2 * 16 + lr;
                const int qrow = qt * 64 + w * 16 + lg * 4 + r;
                if (key > qrow) s = -1e30f;
                p[n2][r] = s;
            }
        float scl[4];
#pragma unroll
        for (int r = 0; r < 4; ++r) {
            float tm = fmaxf(p[0][r], p[1][r]);
            tm = fmaxf(tm, __shfl_xor(tm, 1));
            tm = fmaxf(tm, __shfl_xor(tm, 2));
            tm = fmaxf(tm, __shfl_xor(tm, 4));
            tm = fmaxf(tm, __shfl_xor(tm, 8));
            const float mnew = fmaxf(m_r[r], tm);
            scl[r] = expf(m_r[r] - mnew);
            m_r[r] = mnew;
        }
#pragma unroll
        for (int r = 0; r < 4; ++r) {
            p[0][r] = expf(p[0][r] - m_r[r]);
            p[1][r] = expf(p[1][r] - m_r[r]);
            float ts = p[0][r] + p[1][r];
            ts += __shfl_xor(ts, 1);
            ts += __shfl_xor(ts, 2);
            ts += __shfl_xor(ts, 4);
            ts += __shfl_xor(ts, 8);
            l_r[r] = l_r[r] * scl[r] + ts;
        }
#pragma unroll
        for (int nf = 0; nf < 4; ++nf)
#pragma unroll
            for (int r = 0; r < 4; ++r) oacc[nf][r] *= scl[r];
#pragma unroll
        for (int n2 = 0; n2 < 2; ++n2)
#pragma unroll
            for (int r = 0; r < 4; ++r) {
                unsigned short a, b, c;
                split3(p[n2][r], a, b, c);
                Ps[w][0][lg * 4 + r][n2 * 16 + lr] = a;
                Ps[w][1][lg * 4 + r][n2 * 16 + lr] = b;
                Ps[w][2][lg * 4 + r][n2 * 16 + lr] = c;
            }
        short8_t pa0 = *(const short8_t*)&Ps[w][0][lr][lg * 8];
        short8_t pa1 = *(const short8_t*)&Ps[w][1][lr][lg * 8];
        short8_t pa2 = *(const short8_t*)&Ps[w][2][lr][lg * 8];
#pragma unroll
        for (int nf = 0; nf < 4; ++nf) {
            short8_t vb0 = *(const short8_t*)&Vt[0][nf * 16 + lr][lg * 8];
            short8_t vb1 = *(const short8_t*)&Vt[1][nf * 16 + lr][lg * 8];
            short8_t vb2 = *(const short8_t*)&Vt[2][nf * 16 + lr][lg * 8];
            f32x4_t c = oacc[nf];
            c = MFMA16(pa0, vb0, c);
            c = MFMA16(pa0, vb1, c);
            c = MFMA16(pa1, vb0, c);
            c = MFMA16(pa1, vb1, c);
            c = MFMA16(pa0, vb2, c);
            c = MFMA16(pa2, vb0, c);
            oacc[nf] = c;
        }
    }
    float inv[4];
#pragma unroll
    for (int r = 0; r < 4; ++r) inv[r] = 1.f / l_r[r];
#pragma unroll
    for (int nf = 0; nf < 4; ++nf)
#pragma unroll
        for (int r = 0; r < 4; ++r) {
            const int qrow = qt * 64 + w * 16 + lg * 4 + r;
            const size_t idx = ((size_t)n * S_ + qrow) * D_ + hh * DH_ + nf * 16 + lr;
            unsigned short a, b, c;
            split3(oacc[nf][r] * inv[r], a, b, c);
            hsO[idx] = a; hsO[idx + HSPLANE] = b; hsO[idx + 2 * HSPLANE] = c;
        }
}

// ---------------------------------------------------------------- confidence head (reads split planes 0+1)
__global__ __launch_bounds__(256) void conf_kernel(const unsigned short* __restrict__ hs,
    const float* __restrict__ w, const float* __restrict__ bc, float* __restrict__ conf_out, int k)
{
    const int wid = threadIdx.x >> 6, lane = threadIdx.x & 63;
    const int row = blockIdx.x * 4 + wid;
    const unsigned short* h0 = hs + (size_t)row * D_;
    const unsigned short* h1 = h0 + HSPLANE;
    float sm = 0.f;
#pragma unroll
    for (int j = 0; j < 8; ++j) {
        const int i = lane + 64 * j;
        sm += (b2f(h0[i]) + b2f(h1[i])) * w[i];
    }
#pragma unroll
    for (int off = 32; off; off >>= 1) sm += __shfl_down(sm, off, 64);
    if (lane == 0) {
        const int n = row >> 10, s = row & (S_ - 1);
        conf_out[((size_t)n * K_ + k) * S_ + s] = sm + bc[0];
    }
}

// ---------------------------------------------------------------- per-token CE loss
__global__ __launch_bounds__(256) void loss_kernel(const float* __restrict__ logits,
    const int* __restrict__ y, float* __restrict__ loss)
{
    const int row = blockIdx.x;
    const float* lr = logits + (size_t)row * C_;
    const int tid = threadIdx.x;
    __shared__ float red[256];
    float mx = -1e30f;
    for (int c = tid; c < C_; c += 256) mx = fmaxf(mx, lr[c]);
    red[tid] = mx; __syncthreads();
    for (int st = 128; st > 0; st >>= 1) {
        if (tid < st) red[tid] = fmaxf(red[tid], red[tid + st]);
        __syncthreads();
    }
    mx = red[0];
    __syncthreads();
    float sm = 0.f;
    for (int c = tid; c < C_; c += 256) sm += expf(lr[c] - mx);
    red[tid] = sm; __syncthreads();
    for (int st = 128; st > 0; st >>= 1) {
        if (tid < st) red[tid] += red[tid + st];
        __syncthreads();
    }
    if (tid == 0) loss[row] = logf(red[0]) + mx - lr[y[row]];
}

// ---------------------------------------------------------------- capacity auction: LDS-staged, pre-sorted
__global__ __launch_bounds__(256) void routing_kernel(const float* __restrict__ loss,
    float* __restrict__ idx_out, int* __restrict__ chosen_buf)
{
    __shared__ float l_s[K_][S_];
    __shared__ unsigned char ord_s[S_];
    const int n = blockIdx.x;
    const int tid = threadIdx.x;
#pragma unroll
    for (int k = 0; k < K_; ++k)
        ((float4*)l_s[k])[tid] = ((const float4*)(loss + (size_t)k * M_ + n * S_))[tid];
    __syncthreads();
    for (int s = tid; s < S_; s += 256) {
        float l[K_];
#pragma unroll
        for (int k = 0; k < K_; ++k) l[k] = l_s[k][s];
        int ord[K_] = {0, 1, 2, 3};
#pragma unroll
        for (int i = 1; i < K_; ++i) {
            const int v = ord[i];
            int j = i;
            while (j > 0 && l[ord[j - 1]] > l[v]) { ord[j] = ord[j - 1]; --j; }
            ord[j] = v;
        }
        ord_s[s] = (unsigned char)(ord[0] | (ord[1] << 2) | (ord[2] << 4) | (ord[3] << 6));
    }
    __syncthreads();
    if (tid == 0) {
        int tc[K_] = {0, 0, 0, 0};
        for (int s = 0; s < S_; ++s) {
            const unsigned b = ord_s[s];
            int ch = b & 3;
#pragma unroll
            for (int j = 0; j < K_; ++j) {
                const int m = (b >> (2 * j)) & 3;
                if (tc[m] < CAP_) { ch = m; break; }
            }
            ++tc[ch];
            chosen_buf[n * S_ + s] = ch;
            idx_out[n * S_ + s] = (float)ch;
        }
    }
}

// ----------------------------------------------------------------
extern "C" void kernel_launch(void* const* d_in, const int* in_sizes, int n_in,
                              void* d_out, int out_size, void* d_ws, size_t ws_size,
                              hipStream_t stream)
{
    const int*   x_in = (const int*)d_in[0];
    const int*   y    = (const int*)d_in[1];
    const float* tok  = (const float*)d_in[2];
    const float* pos  = (const float*)d_in[3];
    const float* ln1s = (const float*)d_in[4];
    const float* ln1b = (const float*)d_in[5];
    const float* Wqkv = (const float*)d_in[6];
    const float* bqkv = (const float*)d_in[7];
    const float* Wo   = (const float*)d_in[8];
    const float* bo   = (const float*)d_in[9];
    const float* ln2s = (const float*)d_in[10];
    const float* ln2b = (const float*)d_in[11];
    const float* W1   = (const float*)d_in[12];
    const float* b1   = (const float*)d_in[13];
    const float* W2   = (const float*)d_in[14];
    const float* b2   = (const float*)d_in[15];
    const float* lnfs = (const float*)d_in[16];
    const float* lnfb = (const float*)d_in[17];
    const float* Wcls = (const float*)d_in[18];
    const float* bcls = (const float*)d_in[19];
    const float* Wcnf = (const float*)d_in[20];
    const float* bcnf = (const float*)d_in[21];

    // ws layout (same as passing round-13):
    // R [M][1536] f32 (qkv f32 | mids bf16x3 [3][M][1024] | logits f32 [M][1000])
    // hs [3][M][512]bf16 | x [M][512]f32 | hfin [K][M][512]bf16 | (reserved) | loss [K][M]f32 | chosen [M]i32
    if (ws_size < 66142208) return;   // fail fast instead of corrupting
    float* R = (float*)d_ws;
    unsigned short* hs   = (unsigned short*)(R + (size_t)M_ * 1536);
    float* x             = (float*)(hs + 3 * HSPLANE);
    unsigned short* hfin = (unsigned short*)(x + (size_t)M_ * D_);
    unsigned short* Wt   = hfin + (size_t)K_ * M_ * D_;   // reserved (unused)
    float* loss          = (float*)(Wt + 3 * (size_t)524288);
    int*   chosen        = (int*)(loss + (size_t)K_ * M_);
    unsigned short* mids = (unsigned short*)R;            // mlp mid split planes (qkv dead then)
    const size_t midplane = (size_t)M_ * 1024;

    float* out      = (float*)d_out;                     // [N][S][C]
    float* conf_out = out + (size_t)M_ * C_;             // [N][K][S]
    float* idx_out  = conf_out + (size_t)N_ * K_ * S_;   // [N][S]

    for (int k = 0; k < K_; ++k) {
        embed_kernel<<<(M_ * (D_ / 4) + 255) / 256, 256, 0, stream>>>(
            x_in, tok + (size_t)k * V_ * D_, pos + (size_t)k * S_ * D_, x);
        for (int i = 0; i < NB_; ++i) {
            const size_t ki = (size_t)k * NB_ + i;
            ln_kernel<0><<<M_, 256, 0, stream>>>(x, ln1s + ki * D_, ln1b + ki * D_, hs, nullptr);
            gemm64f<0><<<dim3(24, 32), 256, 0, stream>>>(
                hs, HSPLANE, Wqkv + ki * D_ * 3 * D_, 3 * D_, bqkv + ki * 3 * D_,
                R, 0, 3 * D_, 3 * D_);
            attn_mfma_kernel<<<dim3(S_ / 64, NH_, N_), 256, 0, stream>>>(R, hs);
            gemm64f<1><<<dim3(8, 32), 256, 0, stream>>>(
                hs, HSPLANE, Wo + ki * D_ * D_, D_, bo + ki * D_, x, 0, D_, D_);
            ln_kernel<0><<<M_, 256, 0, stream>>>(x, ln2s + ki * D_, ln2b + ki * D_, hs, nullptr);
            for (int c = 0; c < 2; ++c) {   // MLP over two 1024-col mid chunks (mids in R; qkv dead)
                gemm64f<2><<<dim3(16, 32), 256, 0, stream>>>(
                    hs, HSPLANE, W1 + ki * D_ * HD_ + c * 1024, HD_, b1 + ki * HD_ + c * 1024,
                    mids, midplane, 1024, 1024);
                gemm64f<4><<<dim3(8, 32), 256, 0, stream>>>(
                    mids, midplane, W2 + ki * HD_ * D_ + (size_t)c * 1024 * D_, D_,
                    (c == 0) ? (b2 + ki * D_) : nullptr, x, 0, D_, D_);
            }
        }
        ln_kernel<1><<<M_, 256, 0, stream>>>(x, lnfs + (size_t)k * D_, lnfb + (size_t)k * D_,
                                             hs, hfin + (size_t)k * M_ * D_);
        gemm64f<0><<<dim3(16, 32), 256, 0, stream>>>(
            hs, HSPLANE, Wcls + (size_t)k * D_ * C_, C_, bcls + (size_t)k * C_, R, 0, C_, C_);
        conf_kernel<<<M_ / 4, 256, 0, stream>>>(hs, Wcnf + (size_t)k * D_, bcnf + k, conf_out, k);
        loss_kernel<<<M_, 256, 0, stream>>>(R, y, loss + (size_t)k * M_);
    }
    routing_kernel<<<N_, 256, 0, stream>>>(loss, idx_out, chosen);
    for (int k = 0; k < K_; ++k)
        rerun_kernel<<<dim3(16, 32), 256, 0, stream>>>(
            hfin + (size_t)k * M_ * D_, Wcls + (size_t)k * D_ * C_, bcls + (size_t)k * C_,
            chosen, k, out);
}

// Round 16
// 13532.928 us; speedup vs baseline: 1.3131x; 1.0047x over previous
//
#include <hip/hip_runtime.h>
#include <hip/hip_bf16.h>

#define N_  4
#define S_  1024
#define K_  4
#define V_  32000
#define C_  1000
#define D_  512
#define NH_ 8
#define NB_ 6
#define HD_ 2048
#define DH_ 64
#define CAP_ 256
#define M_  (N_*S_)   // 4096 rows

typedef __attribute__((ext_vector_type(8))) short short8_t;   // 8 bf16 = 4 VGPR
typedef __attribute__((ext_vector_type(4))) float f32x4_t;

#define MFMA16(a,b,c) __builtin_amdgcn_mfma_f32_16x16x32_bf16((a),(b),(c),0,0,0)

#define HSPLANE ((size_t)M_ * D_)        // elems per split plane of hs

static __device__ __forceinline__ float bfround(float v) {   // RNE to bf16, as float
    unsigned u = __float_as_uint(v);
    u = (u + 0x7FFFu + ((u >> 16) & 1u)) & 0xFFFF0000u;
    return __uint_as_float(u);
}
static __device__ __forceinline__ void split3(float v, unsigned short& a, unsigned short& b, unsigned short& c) {
    const float f0 = bfround(v);      const float r1 = v - f0;
    const float f1 = bfround(r1);     const float f2 = bfround(r1 - f1);
    a = (unsigned short)(__float_as_uint(f0) >> 16);
    b = (unsigned short)(__float_as_uint(f1) >> 16);
    c = (unsigned short)(__float_as_uint(f2) >> 16);
}
static __device__ __forceinline__ unsigned short f2bf(float f) {
    unsigned u = __float_as_uint(f);
    return (unsigned short)((u + 0x7FFFu + ((u >> 16) & 1u)) >> 16);
}
static __device__ __forceinline__ float b2f(unsigned short u) {
    return __uint_as_float((unsigned)u << 16);
}

// ---------------------------------------------------------------- embed
__global__ __launch_bounds__(256) void embed_kernel(const int* __restrict__ x_in,
    const float* __restrict__ tok, const float* __restrict__ pos, float* __restrict__ x)
{
    const int idx = blockIdx.x * 256 + threadIdx.x;
    const int total = M_ * (D_ / 4);
    if (idx >= total) return;
    const int d = (idx & (D_ / 4 - 1)) * 4;
    const int row = idx >> 7;
    const int s = row & (S_ - 1);
    const int t = x_in[row];
    const float4 a = *(const float4*)(tok + (size_t)t * D_ + d);
    const float4 b = *(const float4*)(pos + (size_t)s * D_ + d);
    float4 r; r.x = a.x + b.x; r.y = a.y + b.y; r.z = a.z + b.z; r.w = a.w + b.w;
    *(float4*)(x + (size_t)row * D_ + d) = r;
}

// ---------------------------------------------------------------- layernorm -> split bf16x3 planes (FIN: also write hfin plane0)
template<int FIN>
__global__ __launch_bounds__(256) void ln_kernel(const float* __restrict__ x,
    const float* __restrict__ sc, const float* __restrict__ bi, unsigned short* __restrict__ hs,
    unsigned short* __restrict__ hfin)
{
    const int row = blockIdx.x, tid = threadIdx.x;
    const float* xr = x + (size_t)row * D_;
    float v0 = xr[tid], v1 = xr[tid + 256];
    float s1 = v0 + v1;
#pragma unroll
    for (int off = 32; off; off >>= 1) s1 += __shfl_down(s1, off, 64);
    __shared__ float red[8];
    __shared__ float stat[2];
    const int wid = tid >> 6, lane = tid & 63;
    if (lane == 0) red[wid] = s1;
    __syncthreads();
    if (tid == 0) stat[0] = (red[0] + red[1] + red[2] + red[3]) * (1.f / (float)D_);
    __syncthreads();
    const float mean = stat[0];
    const float d0 = v0 - mean, d1 = v1 - mean;
    float s2 = d0 * d0 + d1 * d1;
#pragma unroll
    for (int off = 32; off; off >>= 1) s2 += __shfl_down(s2, off, 64);
    if (lane == 0) red[wid] = s2;
    __syncthreads();
    if (tid == 0) stat[1] = (red[0] + red[1] + red[2] + red[3]) * (1.f / (float)D_);
    __syncthreads();
    const float rstd = rsqrtf(stat[1] + 1e-5f);
    const float o0 = d0 * rstd * sc[tid] + bi[tid];
    const float o1 = d1 * rstd * sc[tid + 256] + bi[tid + 256];
    unsigned short a, b, c;
    const size_t base = (size_t)row * D_ + tid;
    split3(o0, a, b, c);
    hs[base] = a; hs[base + HSPLANE] = b; hs[base + 2 * HSPLANE] = c;
    if (FIN) hfin[base] = a;
    split3(o1, a, b, c);
    hs[base + 256] = a; hs[base + 256 + HSPLANE] = b; hs[base + 256 + 2 * HSPLANE] = c;
    if (FIN) hfin[base + 256] = a;
}

// ---------------------------------------------------------------- fp32-accurate GEMM via bf16x3: A pre-split direct-global,
// B staged from f32 weights with in-kernel split3. block 128x64, 4 waves of 64x32, XCD swizzle (nwg%8==0).
// Round-16: min-occupancy 2 -> 3 blocks/CU (LDS 15KB, est ~120 VGPR -> no spill at 170 cap).
// MODE: 0 = f32 store+bias (KD=512); 1 = f32 += (KD=512); 2 = gelu->split3 planes (KD=512); 4 = f32 += (KD=1024)
template<int MODE>
__global__ __launch_bounds__(256, 3) void gemm64f(const unsigned short* __restrict__ A3, size_t aplane,
    const float* __restrict__ Bf, int ldb, const float* __restrict__ bias,
    void* __restrict__ Cv, size_t cplane, int Nc, int ldc)
{
    constexpr int KD = (MODE == 4) ? 1024 : 512;
    __shared__ __align__(16) unsigned short Bs[3][64][40];
    const int tid = threadIdx.x;
    const int gx = gridDim.x;
    const int nwg = gx * gridDim.y;
    const int bid = blockIdx.y * gx + blockIdx.x;
    const int cpx = nwg >> 3;
    const int swz = (bid & 7) * cpx + (bid >> 3);
    const int bm = (swz / gx) * 128, bn = (swz % gx) * 64;
    const int wid = tid >> 6, lane = tid & 63;
    const int wm = (wid >> 1) * 64, wn = (wid & 1) * 32;
    const int lr = lane & 15, lg = lane >> 4;
    const int scol = tid >> 2, skq = tid & 3;            // B staging: 2-way-free bank pattern
    const int gcol = bn + scol;
    const unsigned short* Ap0 = A3 + (size_t)(bm + wm + lr) * KD + lg * 8;

    f32x4_t acc[4][2] = {};

#pragma unroll
    for (int k0 = 0; k0 < KD; k0 += 32) {
        float bv[8];
        if (gcol < Nc) {
#pragma unroll
            for (int j = 0; j < 8; ++j) bv[j] = Bf[(size_t)(k0 + skq * 8 + j) * ldb + gcol];
        } else {
#pragma unroll
            for (int j = 0; j < 8; ++j) bv[j] = 0.f;
        }
        unsigned short q0[8], q1[8], q2[8];
#pragma unroll
        for (int j = 0; j < 8; ++j) split3(bv[j], q0[j], q1[j], q2[j]);
        short8_t af[3][4];
#pragma unroll
        for (int m = 0; m < 4; ++m) {
            const unsigned short* ap = Ap0 + (size_t)m * 16 * KD + k0;
            af[0][m] = *(const short8_t*)ap;
            af[1][m] = *(const short8_t*)(ap + aplane);
            af[2][m] = *(const short8_t*)(ap + 2 * aplane);
        }
        __syncthreads();   // previous iteration's Bs reads complete
        *(uint4*)&Bs[0][scol][skq * 8] = *(uint4*)&q0[0];
        *(uint4*)&Bs[1][scol][skq * 8] = *(uint4*)&q1[0];
        *(uint4*)&Bs[2][scol][skq * 8] = *(uint4*)&q2[0];
        __syncthreads();
        short8_t bg[3][2];
#pragma unroll
        for (int s = 0; s < 3; ++s)
#pragma unroll
            for (int n2 = 0; n2 < 2; ++n2)
                bg[s][n2] = *(const short8_t*)&Bs[s][wn + n2 * 16 + lr][lg * 8];
#pragma unroll
        for (int m = 0; m < 4; ++m)
#pragma unroll
            for (int n2 = 0; n2 < 2; ++n2) {
                f32x4_t c = acc[m][n2];
                c = MFMA16(af[0][m], bg[0][n2], c);
                c = MFMA16(af[0][m], bg[1][n2], c);
                c = MFMA16(af[1][m], bg[0][n2], c);
                c = MFMA16(af[1][m], bg[1][n2], c);
                c = MFMA16(af[0][m], bg[2][n2], c);
                c = MFMA16(af[2][m], bg[0][n2], c);
                acc[m][n2] = c;
            }
    }
#pragma unroll
    for (int m = 0; m < 4; ++m)
#pragma unroll
        for (int n2 = 0; n2 < 2; ++n2) {
            const int col = bn + wn + n2 * 16 + lr;
            if (col >= Nc) continue;
            const float bv = bias ? bias[col] : 0.f;
            const int row0 = bm + wm + m * 16 + lg * 4;
#pragma unroll
            for (int r = 0; r < 4; ++r) {
                float v = acc[m][n2][r] + bv;
                if (MODE == 2) {
                    const float t = v;
                    v = 0.5f * t * (1.f + tanhf(0.7978845608028654f * (t + 0.044715f * t * t * t)));
                    unsigned short a, b, c;
                    split3(v, a, b, c);
                    unsigned short* Cp = (unsigned short*)Cv + (size_t)(row0 + r) * ldc + col;
                    Cp[0] = a; Cp[cplane] = b; Cp[2 * cplane] = c;
                } else {
                    float* cp = (float*)Cv + (size_t)(row0 + r) * ldc + col;
                    if (MODE == 1 || MODE == 4) v += *cp;
                    *cp = v;
                }
            }
        }
}

// ---------------------------------------------------------------- masked classifier re-run (bf16 single product; W f32 in-kernel cast)
__global__ __launch_bounds__(256) void rerun_kernel(const unsigned short* __restrict__ A,
    const float* __restrict__ Wc, const float* __restrict__ bias,
    const int* __restrict__ chosen, const int kk, float* __restrict__ out)
{
    __shared__ int anyrow;
    const int tid = threadIdx.x;
    const int bm = blockIdx.y * 128, bn = blockIdx.x * 64;
    if (tid == 0) anyrow = 0;
    __syncthreads();
    if (tid < 128 && chosen[bm + tid] == kk) anyrow = 1;
    __syncthreads();
    if (!anyrow) return;
    const int wid = tid >> 6, lane = tid & 63;
    const int wm = (wid >> 1) * 64, wn = (wid & 1) * 32;
    const int lr = lane & 15, lg = lane >> 4;
    f32x4_t acc[4][2] = {};
#pragma unroll
    for (int k0 = 0; k0 < D_; k0 += 32) {
        short8_t af[4], bg[2];
#pragma unroll
        for (int m = 0; m < 4; ++m)
            af[m] = *(const short8_t*)(A + (size_t)(bm + wm + m * 16 + lr) * D_ + k0 + lg * 8);
#pragma unroll
        for (int n2 = 0; n2 < 2; ++n2) {
            const int col = bn + wn + n2 * 16 + lr;
            if (col < C_) {
#pragma unroll
                for (int j = 0; j < 8; ++j)
                    bg[n2][j] = (short)f2bf(Wc[(size_t)(k0 + lg * 8 + j) * C_ + col]);
            } else {
#pragma unroll
                for (int j = 0; j < 8; ++j) bg[n2][j] = 0;
            }
        }
#pragma unroll
        for (int m = 0; m < 4; ++m)
#pragma unroll
            for (int n2 = 0; n2 < 2; ++n2)
                acc[m][n2] = MFMA16(af[m], bg[n2], acc[m][n2]);
    }
#pragma unroll
    for (int m = 0; m < 4; ++m)
#pragma unroll
        for (int n2 = 0; n2 < 2; ++n2) {
            const int col = bn + wn + n2 * 16 + lr;
            if (col >= C_) continue;
            const float bv = bias[col];
            const int row0 = bm + wm + m * 16 + lg * 4;
#pragma unroll
            for (int r = 0; r < 4; ++r) {
                const int row = row0 + r;
                if (chosen[row] == kk) out[(size_t)row * C_ + col] = acc[m][n2][r] + bv;
            }
        }
}

// ---------------------------------------------------------------- MFMA flash attention (bf16x3 split in-kernel), split-bf16 output
__global__ __launch_bounds__(256) void attn_mfma_kernel(const float* __restrict__ qkv, unsigned short* __restrict__ hsO)
{
    __shared__ __align__(16) unsigned short Ks[3][32][72];
    __shared__ __align__(16) unsigned short Vt[3][64][40];
    __shared__ __align__(16) unsigned short Ps[4][3][16][40];
    const int qt = gridDim.x - 1 - blockIdx.x;   // descending: big causal blocks first
    const int hh = blockIdx.y, n = blockIdx.z;
    const int tid = threadIdx.x;
    const int w = tid >> 6, lane = tid & 63;
    const int lr = lane & 15, lg = lane >> 4;
    const size_t rs = 3 * D_;
    const float* base = qkv + (size_t)n * S_ * rs + hh * DH_;

    short8_t qf[3][2];
    {
        const int qrow = qt * 64 + w * 16 + lr;
#pragma unroll
        for (int ks = 0; ks < 2; ++ks) {
            const float* qp = base + (size_t)qrow * rs + ks * 32 + lg * 8;
            float v[8];
            *(float4*)&v[0] = ((const float4*)qp)[0];
            *(float4*)&v[4] = ((const float4*)qp)[1];
#pragma unroll
            for (int j = 0; j < 8; ++j) {
                unsigned short a, b, c;
                split3(v[j], a, b, c);
                qf[0][ks][j] = (short)a; qf[1][ks][j] = (short)b; qf[2][ks][j] = (short)c;
            }
        }
    }

    f32x4_t oacc[4] = {};
    float m_r[4], l_r[4];
#pragma unroll
    for (int r = 0; r < 4; ++r) { m_r[r] = -1e30f; l_r[r] = 0.f; }

    const int ktmax = 2 * qt + 2;
    for (int kt = 0; kt < ktmax; ++kt) {
        __syncthreads();
        {
            const int key = tid & 31, seg = tid >> 5;
            const int kswz = ((key & 3) ^ ((key >> 3) & 3));   // d-block permutation per key
            const float* kp = base + (size_t)(kt * 32 + key) * rs + D_ + seg * 8;
            const float* vp = kp + D_;
            float kv[8], vv[8];
            *(float4*)&kv[0] = ((const float4*)kp)[0];
            *(float4*)&kv[4] = ((const float4*)kp)[1];
            *(float4*)&vv[0] = ((const float4*)vp)[0];
            *(float4*)&vv[4] = ((const float4*)vp)[1];
            unsigned short k0a[8], k1a[8], k2a[8];
#pragma unroll
            for (int j = 0; j < 8; ++j) split3(kv[j], k0a[j], k1a[j], k2a[j]);
            *(uint4*)&Ks[0][key][(seg ^ kswz) * 8] = *(uint4*)&k0a[0];
            *(uint4*)&Ks[1][key][(seg ^ kswz) * 8] = *(uint4*)&k1a[0];
            *(uint4*)&Ks[2][key][(seg ^ kswz) * 8] = *(uint4*)&k2a[0];
#pragma unroll
            for (int j = 0; j < 8; ++j) {
                unsigned short a, b, c;
                split3(vv[j], a, b, c);
                Vt[0][seg * 8 + j][key] = a;
                Vt[1][seg * 8 + j][key] = b;
                Vt[2][seg * 8 + j][key] = c;
            }
        }
        __syncthreads();
        f32x4_t sacc[2] = {};
#pragma unroll
        for (int n2 = 0; n2 < 2; ++n2) {
            const int rk = n2 * 16 + lr;                       // key row being read
            const int rswz = ((rk & 3) ^ ((rk >> 3) & 3));
#pragma unroll
            for (int ks = 0; ks < 2; ++ks) {
                const int boff = ((ks * 4 + lg) ^ rswz) * 8;   // swizzled d-block offset
                short8_t kb0 = *(const short8_t*)&Ks[0][rk][boff];
                short8_t kb1 = *(const short8_t*)&Ks[1][rk][boff];
                short8_t kb2 = *(const short8_t*)&Ks[2][rk][boff];
                f32x4_t c = sacc[n2];
                c = MFMA16(qf[0][ks], kb0, c);
                c = MFMA16(qf[0][ks], kb1, c);
                c = MFMA16(qf[1][ks], kb0, c);
                c = MFMA16(qf[1][ks], kb1, c);
                c = MFMA16(qf[0][ks], kb2, c);
                c = MFMA16(qf[2][ks], kb0, c);
                sacc[n2] = c;
            }
        }
        float p[2][4];
#pragma unroll
        for (int n2 = 0; n2 < 2; ++n2)
#pragma unroll
            for (int r = 0; r < 4; ++r) {
                float s = sacc[n2][r] * 0.125f;
                const int key = kt * 32 + n2 * 16 + lr;
                const int qrow = qt * 64 + w * 16 + lg * 4 + r;
                if (key > qrow) s = -1e30f;
                p[n2][r] = s;
            }
        float scl[4];
#pragma unroll
        for (int r = 0; r < 4; ++r) {
            float tm = fmaxf(p[0][r], p[1][r]);
            tm = fmaxf(tm, __shfl_xor(tm, 1));
            tm = fmaxf(tm, __shfl_xor(tm, 2));
            tm = fmaxf(tm, __shfl_xor(tm, 4));
            tm = fmaxf(tm, __shfl_xor(tm, 8));
            const float mnew = fmaxf(m_r[r], tm);
            scl[r] = expf(m_r[r] - mnew);
            m_r[r] = mnew;
        }
#pragma unroll
        for (int r = 0; r < 4; ++r) {
            p[0][r] = expf(p[0][r] - m_r[r]);
            p[1][r] = expf(p[1][r] - m_r[r]);
            float ts = p[0][r] + p[1][r];
            ts += __shfl_xor(ts, 1);
            ts += __shfl_xor(ts, 2);
            ts += __shfl_xor(ts, 4);
            ts += __shfl_xor(ts, 8);
            l_r[r] = l_r[r] * scl[r] + ts;
        }
#pragma unroll
        for (int nf = 0; nf < 4; ++nf)
#pragma unroll
            for (int r = 0; r < 4; ++r) oacc[nf][r] *= scl[r];
#pragma unroll
        for (int n2 = 0; n2 < 2; ++n2)
#pragma unroll
            for (int r = 0; r < 4; ++r) {
                unsigned short a, b, c;
                split3(p[n2][r], a, b, c);
                Ps[w][0][lg * 4 + r][n2 * 16 + lr] = a;
                Ps[w][1][lg * 4 + r][n2 * 16 + lr] = b;
                Ps[w][2][lg * 4 + r][n2 * 16 + lr] = c;
            }
        short8_t pa0 = *(const short8_t*)&Ps[w][0][lr][lg * 8];
        short8_t pa1 = *(const short8_t*)&Ps[w][1][lr][lg * 8];
        short8_t pa2 = *(const short8_t*)&Ps[w][2][lr][lg * 8];
#pragma unroll
        for (int nf = 0; nf < 4; ++nf) {
            short8_t vb0 = *(const short8_t*)&Vt[0][nf * 16 + lr][lg * 8];
            short8_t vb1 = *(const short8_t*)&Vt[1][nf * 16 + lr][lg * 8];
            short8_t vb2 = *(const short8_t*)&Vt[2][nf * 16 + lr][lg * 8];
            f32x4_t c = oacc[nf];
            c = MFMA16(pa0, vb0, c);
            c = MFMA16(pa0, vb1, c);
            c = MFMA16(pa1, vb0, c);
            c = MFMA16(pa1, vb1, c);
            c = MFMA16(pa0, vb2, c);
            c = MFMA16(pa2, vb0, c);
            oacc[nf] = c;
        }
    }
    float inv[4];
#pragma unroll
    for (int r = 0; r < 4; ++r) inv[r] = 1.f / l_r[r];
#pragma unroll
    for (int nf = 0; nf < 4; ++nf)
#pragma unroll
        for (int r = 0; r < 4; ++r) {
            const int qrow = qt * 64 + w * 16 + lg * 4 + r;
            const size_t idx = ((size_t)n * S_ + qrow) * D_ + hh * DH_ + nf * 16 + lr;
            unsigned short a, b, c;
            split3(oacc[nf][r] * inv[r], a, b, c);
            hsO[idx] = a; hsO[idx + HSPLANE] = b; hsO[idx + 2 * HSPLANE] = c;
        }
}

// ---------------------------------------------------------------- confidence head (reads split planes 0+1)
__global__ __launch_bounds__(256) void conf_kernel(const unsigned short* __restrict__ hs,
    const float* __restrict__ w, const float* __restrict__ bc, float* __restrict__ conf_out, int k)
{
    const int wid = threadIdx.x >> 6, lane = threadIdx.x & 63;
    const int row = blockIdx.x * 4 + wid;
    const unsigned short* h0 = hs + (size_t)row * D_;
    const unsigned short* h1 = h0 + HSPLANE;
    float sm = 0.f;
#pragma unroll
    for (int j = 0; j < 8; ++j) {
        const int i = lane + 64 * j;
        sm += (b2f(h0[i]) + b2f(h1[i])) * w[i];
    }
#pragma unroll
    for (int off = 32; off; off >>= 1) sm += __shfl_down(sm, off, 64);
    if (lane == 0) {
        const int n = row >> 10, s = row & (S_ - 1);
        conf_out[((size_t)n * K_ + k) * S_ + s] = sm + bc[0];
    }
}

// ---------------------------------------------------------------- per-token CE loss
__global__ __launch_bounds__(256) void loss_kernel(const float* __restrict__ logits,
    const int* __restrict__ y, float* __restrict__ loss)
{
    const int row = blockIdx.x;
    const float* lr = logits + (size_t)row * C_;
    const int tid = threadIdx.x;
    __shared__ float red[256];
    float mx = -1e30f;
    for (int c = tid; c < C_; c += 256) mx = fmaxf(mx, lr[c]);
    red[tid] = mx; __syncthreads();
    for (int st = 128; st > 0; st >>= 1) {
        if (tid < st) red[tid] = fmaxf(red[tid], red[tid + st]);
        __syncthreads();
    }
    mx = red[0];
    __syncthreads();
    float sm = 0.f;
    for (int c = tid; c < C_; c += 256) sm += expf(lr[c] - mx);
    red[tid] = sm; __syncthreads();
    for (int st = 128; st > 0; st >>= 1) {
        if (tid < st) red[tid] += red[tid + st];
        __syncthreads();
    }
    if (tid == 0) loss[row] = logf(red[0]) + mx - lr[y[row]];
}

// ---------------------------------------------------------------- capacity auction: LDS-staged, pre-sorted
__global__ __launch_bounds__(256) void routing_kernel(const float* __restrict__ loss,
    float* __restrict__ idx_out, int* __restrict__ chosen_buf)
{
    __shared__ float l_s[K_][S_];
    __shared__ unsigned char ord_s[S_];
    const int n = blockIdx.x;
    const int tid = threadIdx.x;
#pragma unroll
    for (int k = 0; k < K_; ++k)
        ((float4*)l_s[k])[tid] = ((const float4*)(loss + (size_t)k * M_ + n * S_))[tid];
    __syncthreads();
    for (int s = tid; s < S_; s += 256) {
        float l[K_];
#pragma unroll
        for (int k = 0; k < K_; ++k) l[k] = l_s[k][s];
        int ord[K_] = {0, 1, 2, 3};
#pragma unroll
        for (int i = 1; i < K_; ++i) {
            const int v = ord[i];
            int j = i;
            while (j > 0 && l[ord[j - 1]] > l[v]) { ord[j] = ord[j - 1]; --j; }
            ord[j] = v;
        }
        ord_s[s] = (unsigned char)(ord[0] | (ord[1] << 2) | (ord[2] << 4) | (ord[3] << 6));
    }
    __syncthreads();
    if (tid == 0) {
        int tc[K_] = {0, 0, 0, 0};
        for (int s = 0; s < S_; ++s) {
            const unsigned b = ord_s[s];
            int ch = b & 3;
#pragma unroll
            for (int j = 0; j < K_; ++j) {
                const int m = (b >> (2 * j)) & 3;
                if (tc[m] < CAP_) { ch = m; break; }
            }
            ++tc[ch];
            chosen_buf[n * S_ + s] = ch;
            idx_out[n * S_ + s] = (float)ch;
        }
    }
}

// ----------------------------------------------------------------
extern "C" void kernel_launch(void* const* d_in, const int* in_sizes, int n_in,
                              void* d_out, int out_size, void* d_ws, size_t ws_size,
                              hipStream_t stream)
{
    const int*   x_in = (const int*)d_in[0];
    const int*   y    = (const int*)d_in[1];
    const float* tok  = (const float*)d_in[2];
    const float* pos  = (const float*)d_in[3];
    const float* ln1s = (const float*)d_in[4];
    const float* ln1b = (const float*)d_in[5];
    const float* Wqkv = (const float*)d_in[6];
    const float* bqkv = (const float*)d_in[7];
    const float* Wo   = (const float*)d_in[8];
    const float* bo   = (const float*)d_in[9];
    const float* ln2s = (const float*)d_in[10];
    const float* ln2b = (const float*)d_in[11];
    const float* W1   = (const float*)d_in[12];
    const float* b1   = (const float*)d_in[13];
    const float* W2   = (const float*)d_in[14];
    const float* b2   = (const float*)d_in[15];
    const float* lnfs = (const float*)d_in[16];
    const float* lnfb = (const float*)d_in[17];
    const float* Wcls = (const float*)d_in[18];
    const float* bcls = (const float*)d_in[19];
    const float* Wcnf = (const float*)d_in[20];
    const float* bcnf = (const float*)d_in[21];

    // ws layout (same as passing round-13):
    // R [M][1536] f32 (qkv f32 | mids bf16x3 [3][M][1024] | logits f32 [M][1000])
    // hs [3][M][512]bf16 | x [M][512]f32 | hfin [K][M][512]bf16 | (reserved) | loss [K][M]f32 | chosen [M]i32
    if (ws_size < 66142208) return;   // fail fast instead of corrupting
    float* R = (float*)d_ws;
    unsigned short* hs   = (unsigned short*)(R + (size_t)M_ * 1536);
    float* x             = (float*)(hs + 3 * HSPLANE);
    unsigned short* hfin = (unsigned short*)(x + (size_t)M_ * D_);
    unsigned short* Wt   = hfin + (size_t)K_ * M_ * D_;   // reserved (unused)
    float* loss          = (float*)(Wt + 3 * (size_t)524288);
    int*   chosen        = (int*)(loss + (size_t)K_ * M_);
    unsigned short* mids = (unsigned short*)R;            // mlp mid split planes (qkv dead then)
    const size_t midplane = (size_t)M_ * 1024;

    float* out      = (float*)d_out;                     // [N][S][C]
    float* conf_out = out + (size_t)M_ * C_;             // [N][K][S]
    float* idx_out  = conf_out + (size_t)N_ * K_ * S_;   // [N][S]

    for (int k = 0; k < K_; ++k) {
        embed_kernel<<<(M_ * (D_ / 4) + 255) / 256, 256, 0, stream>>>(
            x_in, tok + (size_t)k * V_ * D_, pos + (size_t)k * S_ * D_, x);
        for (int i = 0; i < NB_; ++i) {
            const size_t ki = (size_t)k * NB_ + i;
            ln_kernel<0><<<M_, 256, 0, stream>>>(x, ln1s + ki * D_, ln1b + ki * D_, hs, nullptr);
            gemm64f<0><<<dim3(24, 32), 256, 0, stream>>>(
                hs, HSPLANE, Wqkv + ki * D_ * 3 * D_, 3 * D_, bqkv + ki * 3 * D_,
                R, 0, 3 * D_, 3 * D_);
            attn_mfma_kernel<<<dim3(S_ / 64, NH_, N_), 256, 0, stream>>>(R, hs);
            gemm64f<1><<<dim3(8, 32), 256, 0, stream>>>(
                hs, HSPLANE, Wo + ki * D_ * D_, D_, bo + ki * D_, x, 0, D_, D_);
            ln_kernel<0><<<M_, 256, 0, stream>>>(x, ln2s + ki * D_, ln2b + ki * D_, hs, nullptr);
            for (int c = 0; c < 2; ++c) {   // MLP over two 1024-col mid chunks (mids in R; qkv dead)
                gemm64f<2><<<dim3(16, 32), 256, 0, stream>>>(
                    hs, HSPLANE, W1 + ki * D_ * HD_ + c * 1024, HD_, b1 + ki * HD_ + c * 1024,
                    mids, midplane, 1024, 1024);
                gemm64f<4><<<dim3(8, 32), 256, 0, stream>>>(
                    mids, midplane, W2 + ki * HD_ * D_ + (size_t)c * 1024 * D_, D_,
                    (c == 0) ? (b2 + ki * D_) : nullptr, x, 0, D_, D_);
            }
        }
        ln_kernel<1><<<M_, 256, 0, stream>>>(x, lnfs + (size_t)k * D_, lnfb + (size_t)k * D_,
                                             hs, hfin + (size_t)k * M_ * D_);
        gemm64f<0><<<dim3(16, 32), 256, 0, stream>>>(
            hs, HSPLANE, Wcls + (size_t)k * D_ * C_, C_, bcls + (size_t)k * C_, R, 0, C_, C_);
        conf_kernel<<<M_ / 4, 256, 0, stream>>>(hs, Wcnf + (size_t)k * D_, bcnf + k, conf_out, k);
        loss_kernel<<<M_, 256, 0, stream>>>(R, y, loss + (size_t)k * M_);
    }
    routing_kernel<<<N_, 256, 0, stream>>>(loss, idx_out, chosen);
    for (int k = 0; k < K_; ++k)
        rerun_kernel<<<dim3(16, 32), 256, 0, stream>>>(
            hfin + (size_t)k * M_ * D_, Wcls + (size_t)k * D_ * C_, bcls + (size_t)k * C_,
            chosen, k, out);
}

// Round 17
// 12753.803 us; speedup vs baseline: 1.3933x; 1.0611x over previous
//
#include <hip/hip_runtime.h>
#include <hip/hip_bf16.h>

#define N_  4
#define S_  1024
#define K_  4
#define V_  32000
#define C_  1000
#define D_  512
#define NH_ 8
#define NB_ 6
#define HD_ 2048
#define DH_ 64
#define CAP_ 256
#define M_  (N_*S_)   // 4096 rows

typedef __attribute__((ext_vector_type(8))) short short8_t;   // 8 bf16 = 4 VGPR
typedef __attribute__((ext_vector_type(4))) float f32x4_t;

#define MFMA16(a,b,c) __builtin_amdgcn_mfma_f32_16x16x32_bf16((a),(b),(c),0,0,0)

#define HSPLANE ((size_t)M_ * D_)        // elems per split plane of hs

static __device__ __forceinline__ float bfround(float v) {   // RNE to bf16, as float
    unsigned u = __float_as_uint(v);
    u = (u + 0x7FFFu + ((u >> 16) & 1u)) & 0xFFFF0000u;
    return __uint_as_float(u);
}
static __device__ __forceinline__ void split3(float v, unsigned short& a, unsigned short& b, unsigned short& c) {
    const float f0 = bfround(v);      const float r1 = v - f0;
    const float f1 = bfround(r1);     const float f2 = bfround(r1 - f1);
    a = (unsigned short)(__float_as_uint(f0) >> 16);
    b = (unsigned short)(__float_as_uint(f1) >> 16);
    c = (unsigned short)(__float_as_uint(f2) >> 16);
}
static __device__ __forceinline__ unsigned short f2bf(float f) {
    unsigned u = __float_as_uint(f);
    return (unsigned short)((u + 0x7FFFu + ((u >> 16) & 1u)) >> 16);
}
static __device__ __forceinline__ float b2f(unsigned short u) {
    return __uint_as_float((unsigned)u << 16);
}

// ---------------------------------------------------------------- embed
__global__ __launch_bounds__(256) void embed_kernel(const int* __restrict__ x_in,
    const float* __restrict__ tok, const float* __restrict__ pos, float* __restrict__ x)
{
    const int idx = blockIdx.x * 256 + threadIdx.x;
    const int total = M_ * (D_ / 4);
    if (idx >= total) return;
    const int d = (idx & (D_ / 4 - 1)) * 4;
    const int row = idx >> 7;
    const int s = row & (S_ - 1);
    const int t = x_in[row];
    const float4 a = *(const float4*)(tok + (size_t)t * D_ + d);
    const float4 b = *(const float4*)(pos + (size_t)s * D_ + d);
    float4 r; r.x = a.x + b.x; r.y = a.y + b.y; r.z = a.z + b.z; r.w = a.w + b.w;
    *(float4*)(x + (size_t)row * D_ + d) = r;
}

// ---------------------------------------------------------------- layernorm -> split bf16x3 planes (FIN: also write hfin plane0)
template<int FIN>
__global__ __launch_bounds__(256) void ln_kernel(const float* __restrict__ x,
    const float* __restrict__ sc, const float* __restrict__ bi, unsigned short* __restrict__ hs,
    unsigned short* __restrict__ hfin)
{
    const int row = blockIdx.x, tid = threadIdx.x;
    const float* xr = x + (size_t)row * D_;
    float v0 = xr[tid], v1 = xr[tid + 256];
    float s1 = v0 + v1;
#pragma unroll
    for (int off = 32; off; off >>= 1) s1 += __shfl_down(s1, off, 64);
    __shared__ float red[8];
    __shared__ float stat[2];
    const int wid = tid >> 6, lane = tid & 63;
    if (lane == 0) red[wid] = s1;
    __syncthreads();
    if (tid == 0) stat[0] = (red[0] + red[1] + red[2] + red[3]) * (1.f / (float)D_);
    __syncthreads();
    const float mean = stat[0];
    const float d0 = v0 - mean, d1 = v1 - mean;
    float s2 = d0 * d0 + d1 * d1;
#pragma unroll
    for (int off = 32; off; off >>= 1) s2 += __shfl_down(s2, off, 64);
    if (lane == 0) red[wid] = s2;
    __syncthreads();
    if (tid == 0) stat[1] = (red[0] + red[1] + red[2] + red[3]) * (1.f / (float)D_);
    __syncthreads();
    const float rstd = rsqrtf(stat[1] + 1e-5f);
    const float o0 = d0 * rstd * sc[tid] + bi[tid];
    const float o1 = d1 * rstd * sc[tid + 256] + bi[tid + 256];
    unsigned short a, b, c;
    const size_t base = (size_t)row * D_ + tid;
    split3(o0, a, b, c);
    hs[base] = a; hs[base + HSPLANE] = b; hs[base + 2 * HSPLANE] = c;
    if (FIN) hfin[base] = a;
    split3(o1, a, b, c);
    hs[base + 256] = a; hs[base + 256 + HSPLANE] = b; hs[base + 256 + 2 * HSPLANE] = c;
    if (FIN) hfin[base + 256] = a;
}

// ---------------------------------------------------------------- fp32-accurate GEMM via bf16x3: A pre-split direct-global,
// B staged from f32 weights with in-kernel split3. block 128x64, 4 waves of 64x32, XCD swizzle (nwg%8==0).
// Round-17: explicit software pipeline — next K-step's A-frags + B-row are loaded into dedicated
// registers BEFORE the MFMA block (forces in-flight loads; breaks the VGPR=64 latency serialization).
// MODE: 0 = f32 store+bias (KD=512); 1 = f32 += (KD=512); 2 = gelu->split3 planes (KD=512); 4 = f32 += (KD=1024)
template<int MODE>
__global__ __launch_bounds__(256) void gemm64f(const unsigned short* __restrict__ A3, size_t aplane,
    const float* __restrict__ Bf, int ldb, const float* __restrict__ bias,
    void* __restrict__ Cv, size_t cplane, int Nc, int ldc)
{
    constexpr int KD = (MODE == 4) ? 1024 : 512;
    __shared__ __align__(16) unsigned short Bs[3][64][40];
    const int tid = threadIdx.x;
    const int gx = gridDim.x;
    const int nwg = gx * gridDim.y;
    const int bid = blockIdx.y * gx + blockIdx.x;
    const int cpx = nwg >> 3;
    const int swz = (bid & 7) * cpx + (bid >> 3);
    const int bm = (swz / gx) * 128, bn = (swz % gx) * 64;
    const int wid = tid >> 6, lane = tid & 63;
    const int wm = (wid >> 1) * 64, wn = (wid & 1) * 32;
    const int lr = lane & 15, lg = lane >> 4;
    const int scol = tid >> 2, skq = tid & 3;            // B staging: 2-way-free bank pattern
    const int gcol = bn + scol;
    const unsigned short* Ap0 = A3 + (size_t)(bm + wm + lr) * KD + lg * 8;

    f32x4_t acc[4][2] = {};

    // ---- prologue prefetch (k0 = 0)
    float bv[8];
    if (gcol < Nc) {
#pragma unroll
        for (int j = 0; j < 8; ++j) bv[j] = Bf[(size_t)(skq * 8 + j) * ldb + gcol];
    } else {
#pragma unroll
        for (int j = 0; j < 8; ++j) bv[j] = 0.f;
    }
    short8_t af[3][4];
#pragma unroll
    for (int m = 0; m < 4; ++m) {
        const unsigned short* ap = Ap0 + (size_t)m * 16 * KD;
        af[0][m] = *(const short8_t*)ap;
        af[1][m] = *(const short8_t*)(ap + aplane);
        af[2][m] = *(const short8_t*)(ap + 2 * aplane);
    }

#pragma unroll
    for (int k0 = 0; k0 < KD; k0 += 32) {
        unsigned short q0[8], q1[8], q2[8];
#pragma unroll
        for (int j = 0; j < 8; ++j) split3(bv[j], q0[j], q1[j], q2[j]);
        __syncthreads();   // previous iteration's Bs reads complete
        *(uint4*)&Bs[0][scol][skq * 8] = *(uint4*)&q0[0];
        *(uint4*)&Bs[1][scol][skq * 8] = *(uint4*)&q1[0];
        *(uint4*)&Bs[2][scol][skq * 8] = *(uint4*)&q2[0];
        __syncthreads();
        // ---- issue next K-step's global loads NOW; they fly under the MFMA block below
        float bvn[8];
        short8_t afn[3][4];
        if (k0 + 32 < KD) {
            const int k1 = k0 + 32;
            if (gcol < Nc) {
#pragma unroll
                for (int j = 0; j < 8; ++j) bvn[j] = Bf[(size_t)(k1 + skq * 8 + j) * ldb + gcol];
            } else {
#pragma unroll
                for (int j = 0; j < 8; ++j) bvn[j] = 0.f;
            }
#pragma unroll
            for (int m = 0; m < 4; ++m) {
                const unsigned short* ap = Ap0 + (size_t)m * 16 * KD + k1;
                afn[0][m] = *(const short8_t*)ap;
                afn[1][m] = *(const short8_t*)(ap + aplane);
                afn[2][m] = *(const short8_t*)(ap + 2 * aplane);
            }
        }
        short8_t bg[3][2];
#pragma unroll
        for (int s = 0; s < 3; ++s)
#pragma unroll
            for (int n2 = 0; n2 < 2; ++n2)
                bg[s][n2] = *(const short8_t*)&Bs[s][wn + n2 * 16 + lr][lg * 8];
#pragma unroll
        for (int m = 0; m < 4; ++m)
#pragma unroll
            for (int n2 = 0; n2 < 2; ++n2) {
                f32x4_t c = acc[m][n2];
                c = MFMA16(af[0][m], bg[0][n2], c);
                c = MFMA16(af[0][m], bg[1][n2], c);
                c = MFMA16(af[1][m], bg[0][n2], c);
                c = MFMA16(af[1][m], bg[1][n2], c);
                c = MFMA16(af[0][m], bg[2][n2], c);
                c = MFMA16(af[2][m], bg[0][n2], c);
                acc[m][n2] = c;
            }
        if (k0 + 32 < KD) {   // rotate pipeline registers
#pragma unroll
            for (int j = 0; j < 8; ++j) bv[j] = bvn[j];
#pragma unroll
            for (int m = 0; m < 4; ++m) {
                af[0][m] = afn[0][m];
                af[1][m] = afn[1][m];
                af[2][m] = afn[2][m];
            }
        }
    }
#pragma unroll
    for (int m = 0; m < 4; ++m)
#pragma unroll
        for (int n2 = 0; n2 < 2; ++n2) {
            const int col = bn + wn + n2 * 16 + lr;
            if (col >= Nc) continue;
            const float bv2 = bias ? bias[col] : 0.f;
            const int row0 = bm + wm + m * 16 + lg * 4;
#pragma unroll
            for (int r = 0; r < 4; ++r) {
                float v = acc[m][n2][r] + bv2;
                if (MODE == 2) {
                    const float t = v;
                    v = 0.5f * t * (1.f + tanhf(0.7978845608028654f * (t + 0.044715f * t * t * t)));
                    unsigned short a, b, c;
                    split3(v, a, b, c);
                    unsigned short* Cp = (unsigned short*)Cv + (size_t)(row0 + r) * ldc + col;
                    Cp[0] = a; Cp[cplane] = b; Cp[2 * cplane] = c;
                } else {
                    float* cp = (float*)Cv + (size_t)(row0 + r) * ldc + col;
                    if (MODE == 1 || MODE == 4) v += *cp;
                    *cp = v;
                }
            }
        }
}

// ---------------------------------------------------------------- masked classifier re-run (bf16 single product; W f32 in-kernel cast)
__global__ __launch_bounds__(256) void rerun_kernel(const unsigned short* __restrict__ A,
    const float* __restrict__ Wc, const float* __restrict__ bias,
    const int* __restrict__ chosen, const int kk, float* __restrict__ out)
{
    __shared__ int anyrow;
    const int tid = threadIdx.x;
    const int bm = blockIdx.y * 128, bn = blockIdx.x * 64;
    if (tid == 0) anyrow = 0;
    __syncthreads();
    if (tid < 128 && chosen[bm + tid] == kk) anyrow = 1;
    __syncthreads();
    if (!anyrow) return;
    const int wid = tid >> 6, lane = tid & 63;
    const int wm = (wid >> 1) * 64, wn = (wid & 1) * 32;
    const int lr = lane & 15, lg = lane >> 4;
    f32x4_t acc[4][2] = {};
#pragma unroll
    for (int k0 = 0; k0 < D_; k0 += 32) {
        short8_t af[4], bg[2];
#pragma unroll
        for (int m = 0; m < 4; ++m)
            af[m] = *(const short8_t*)(A + (size_t)(bm + wm + m * 16 + lr) * D_ + k0 + lg * 8);
#pragma unroll
        for (int n2 = 0; n2 < 2; ++n2) {
            const int col = bn + wn + n2 * 16 + lr;
            if (col < C_) {
#pragma unroll
                for (int j = 0; j < 8; ++j)
                    bg[n2][j] = (short)f2bf(Wc[(size_t)(k0 + lg * 8 + j) * C_ + col]);
            } else {
#pragma unroll
                for (int j = 0; j < 8; ++j) bg[n2][j] = 0;
            }
        }
#pragma unroll
        for (int m = 0; m < 4; ++m)
#pragma unroll
            for (int n2 = 0; n2 < 2; ++n2)
                acc[m][n2] = MFMA16(af[m], bg[n2], acc[m][n2]);
    }
#pragma unroll
    for (int m = 0; m < 4; ++m)
#pragma unroll
        for (int n2 = 0; n2 < 2; ++n2) {
            const int col = bn + wn + n2 * 16 + lr;
            if (col >= C_) continue;
            const float bv = bias[col];
            const int row0 = bm + wm + m * 16 + lg * 4;
#pragma unroll
            for (int r = 0; r < 4; ++r) {
                const int row = row0 + r;
                if (chosen[row] == kk) out[(size_t)row * C_ + col] = acc[m][n2][r] + bv;
            }
        }
}

// ---------------------------------------------------------------- MFMA flash attention (bf16x3 split in-kernel), split-bf16 output
__global__ __launch_bounds__(256) void attn_mfma_kernel(const float* __restrict__ qkv, unsigned short* __restrict__ hsO)
{
    __shared__ __align__(16) unsigned short Ks[3][32][72];
    __shared__ __align__(16) unsigned short Vt[3][64][40];
    __shared__ __align__(16) unsigned short Ps[4][3][16][40];
    const int qt = gridDim.x - 1 - blockIdx.x;   // descending: big causal blocks first
    const int hh = blockIdx.y, n = blockIdx.z;
    const int tid = threadIdx.x;
    const int w = tid >> 6, lane = tid & 63;
    const int lr = lane & 15, lg = lane >> 4;
    const size_t rs = 3 * D_;
    const float* base = qkv + (size_t)n * S_ * rs + hh * DH_;

    short8_t qf[3][2];
    {
        const int qrow = qt * 64 + w * 16 + lr;
#pragma unroll
        for (int ks = 0; ks < 2; ++ks) {
            const float* qp = base + (size_t)qrow * rs + ks * 32 + lg * 8;
            float v[8];
            *(float4*)&v[0] = ((const float4*)qp)[0];
            *(float4*)&v[4] = ((const float4*)qp)[1];
#pragma unroll
            for (int j = 0; j < 8; ++j) {
                unsigned short a, b, c;
                split3(v[j], a, b, c);
                qf[0][ks][j] = (short)a; qf[1][ks][j] = (short)b; qf[2][ks][j] = (short)c;
            }
        }
    }

    f32x4_t oacc[4] = {};
    float m_r[4], l_r[4];
#pragma unroll
    for (int r = 0; r < 4; ++r) { m_r[r] = -1e30f; l_r[r] = 0.f; }

    const int ktmax = 2 * qt + 2;
    for (int kt = 0; kt < ktmax; ++kt) {
        __syncthreads();
        {
            const int key = tid & 31, seg = tid >> 5;
            const int kswz = ((key & 3) ^ ((key >> 3) & 3));   // d-block permutation per key
            const float* kp = base + (size_t)(kt * 32 + key) * rs + D_ + seg * 8;
            const float* vp = kp + D_;
            float kv[8], vv[8];
            *(float4*)&kv[0] = ((const float4*)kp)[0];
            *(float4*)&kv[4] = ((const float4*)kp)[1];
            *(float4*)&vv[0] = ((const float4*)vp)[0];
            *(float4*)&vv[4] = ((const float4*)vp)[1];
            unsigned short k0a[8], k1a[8], k2a[8];
#pragma unroll
            for (int j = 0; j < 8; ++j) split3(kv[j], k0a[j], k1a[j], k2a[j]);
            *(uint4*)&Ks[0][key][(seg ^ kswz) * 8] = *(uint4*)&k0a[0];
            *(uint4*)&Ks[1][key][(seg ^ kswz) * 8] = *(uint4*)&k1a[0];
            *(uint4*)&Ks[2][key][(seg ^ kswz) * 8] = *(uint4*)&k2a[0];
#pragma unroll
            for (int j = 0; j < 8; ++j) {
                unsigned short a, b, c;
                split3(vv[j], a, b, c);
                Vt[0][seg * 8 + j][key] = a;
                Vt[1][seg * 8 + j][key] = b;
                Vt[2][seg * 8 + j][key] = c;
            }
        }
        __syncthreads();
        f32x4_t sacc[2] = {};
#pragma unroll
        for (int n2 = 0; n2 < 2; ++n2) {
            const int rk = n2 * 16 + lr;                       // key row being read
            const int rswz = ((rk & 3) ^ ((rk >> 3) & 3));
#pragma unroll
            for (int ks = 0; ks < 2; ++ks) {
                const int boff = ((ks * 4 + lg) ^ rswz) * 8;   // swizzled d-block offset
                short8_t kb0 = *(const short8_t*)&Ks[0][rk][boff];
                short8_t kb1 = *(const short8_t*)&Ks[1][rk][boff];
                short8_t kb2 = *(const short8_t*)&Ks[2][rk][boff];
                f32x4_t c = sacc[n2];
                c = MFMA16(qf[0][ks], kb0, c);
                c = MFMA16(qf[0][ks], kb1, c);
                c = MFMA16(qf[1][ks], kb0, c);
                c = MFMA16(qf[1][ks], kb1, c);
                c = MFMA16(qf[0][ks], kb2, c);
                c = MFMA16(qf[2][ks], kb0, c);
                sacc[n2] = c;
            }
        }
        float p[2][4];
#pragma unroll
        for (int n2 = 0; n2 < 2; ++n2)
#pragma unroll
            for (int r = 0; r < 4; ++r) {
                float s = sacc[n2][r] * 0.125f;
                const int key = kt * 32 + n2 * 16 + lr;
                const int qrow = qt * 64 + w * 16 + lg * 4 + r;
                if (key > qrow) s = -1e30f;
                p[n2][r] = s;
            }
        float scl[4];
#pragma unroll
        for (int r = 0; r < 4; ++r) {
            float tm = fmaxf(p[0][r], p[1][r]);
            tm = fmaxf(tm, __shfl_xor(tm, 1));
            tm = fmaxf(tm, __shfl_xor(tm, 2));
            tm = fmaxf(tm, __shfl_xor(tm, 4));
            tm = fmaxf(tm, __shfl_xor(tm, 8));
            const float mnew = fmaxf(m_r[r], tm);
            scl[r] = expf(m_r[r] - mnew);
            m_r[r] = mnew;
        }
#pragma unroll
        for (int r = 0; r < 4; ++r) {
            p[0][r] = expf(p[0][r] - m_r[r]);
            p[1][r] = expf(p[1][r] - m_r[r]);
            float ts = p[0][r] + p[1][r];
            ts += __shfl_xor(ts, 1);
            ts += __shfl_xor(ts, 2);
            ts += __shfl_xor(ts, 4);
            ts += __shfl_xor(ts, 8);
            l_r[r] = l_r[r] * scl[r] + ts;
        }
#pragma unroll
        for (int nf = 0; nf < 4; ++nf)
#pragma unroll
            for (int r = 0; r < 4; ++r) oacc[nf][r] *= scl[r];
#pragma unroll
        for (int n2 = 0; n2 < 2; ++n2)
#pragma unroll
            for (int r = 0; r < 4; ++r) {
                unsigned short a, b, c;
                split3(p[n2][r], a, b, c);
                Ps[w][0][lg * 4 + r][n2 * 16 + lr] = a;
                Ps[w][1][lg * 4 + r][n2 * 16 + lr] = b;
                Ps[w][2][lg * 4 + r][n2 * 16 + lr] = c;
            }
        short8_t pa0 = *(const short8_t*)&Ps[w][0][lr][lg * 8];
        short8_t pa1 = *(const short8_t*)&Ps[w][1][lr][lg * 8];
        short8_t pa2 = *(const short8_t*)&Ps[w][2][lr][lg * 8];
#pragma unroll
        for (int nf = 0; nf < 4; ++nf) {
            short8_t vb0 = *(const short8_t*)&Vt[0][nf * 16 + lr][lg * 8];
            short8_t vb1 = *(const short8_t*)&Vt[1][nf * 16 + lr][lg * 8];
            short8_t vb2 = *(const short8_t*)&Vt[2][nf * 16 + lr][lg * 8];
            f32x4_t c = oacc[nf];
            c = MFMA16(pa0, vb0, c);
            c = MFMA16(pa0, vb1, c);
            c = MFMA16(pa1, vb0, c);
            c = MFMA16(pa1, vb1, c);
            c = MFMA16(pa0, vb2, c);
            c = MFMA16(pa2, vb0, c);
            oacc[nf] = c;
        }
    }
    float inv[4];
#pragma unroll
    for (int r = 0; r < 4; ++r) inv[r] = 1.f / l_r[r];
#pragma unroll
    for (int nf = 0; nf < 4; ++nf)
#pragma unroll
        for (int r = 0; r < 4; ++r) {
            const int qrow = qt * 64 + w * 16 + lg * 4 + r;
            const size_t idx = ((size_t)n * S_ + qrow) * D_ + hh * DH_ + nf * 16 + lr;
            unsigned short a, b, c;
            split3(oacc[nf][r] * inv[r], a, b, c);
            hsO[idx] = a; hsO[idx + HSPLANE] = b; hsO[idx + 2 * HSPLANE] = c;
        }
}

// ---------------------------------------------------------------- confidence head (reads split planes 0+1)
__global__ __launch_bounds__(256) void conf_kernel(const unsigned short* __restrict__ hs,
    const float* __restrict__ w, const float* __restrict__ bc, float* __restrict__ conf_out, int k)
{
    const int wid = threadIdx.x >> 6, lane = threadIdx.x & 63;
    const int row = blockIdx.x * 4 + wid;
    const unsigned short* h0 = hs + (size_t)row * D_;
    const unsigned short* h1 = h0 + HSPLANE;
    float sm = 0.f;
#pragma unroll
    for (int j = 0; j < 8; ++j) {
        const int i = lane + 64 * j;
        sm += (b2f(h0[i]) + b2f(h1[i])) * w[i];
    }
#pragma unroll
    for (int off = 32; off; off >>= 1) sm += __shfl_down(sm, off, 64);
    if (lane == 0) {
        const int n = row >> 10, s = row & (S_ - 1);
        conf_out[((size_t)n * K_ + k) * S_ + s] = sm + bc[0];
    }
}

// ---------------------------------------------------------------- per-token CE loss
__global__ __launch_bounds__(256) void loss_kernel(const float* __restrict__ logits,
    const int* __restrict__ y, float* __restrict__ loss)
{
    const int row = blockIdx.x;
    const float* lr = logits + (size_t)row * C_;
    const int tid = threadIdx.x;
    __shared__ float red[256];
    float mx = -1e30f;
    for (int c = tid; c < C_; c += 256) mx = fmaxf(mx, lr[c]);
    red[tid] = mx; __syncthreads();
    for (int st = 128; st > 0; st >>= 1) {
        if (tid < st) red[tid] = fmaxf(red[tid], red[tid + st]);
        __syncthreads();
    }
    mx = red[0];
    __syncthreads();
    float sm = 0.f;
    for (int c = tid; c < C_; c += 256) sm += expf(lr[c] - mx);
    red[tid] = sm; __syncthreads();
    for (int st = 128; st > 0; st >>= 1) {
        if (tid < st) red[tid] += red[tid + st];
        __syncthreads();
    }
    if (tid == 0) loss[row] = logf(red[0]) + mx - lr[y[row]];
}

// ---------------------------------------------------------------- capacity auction: LDS-staged, pre-sorted
__global__ __launch_bounds__(256) void routing_kernel(const float* __restrict__ loss,
    float* __restrict__ idx_out, int* __restrict__ chosen_buf)
{
    __shared__ float l_s[K_][S_];
    __shared__ unsigned char ord_s[S_];
    const int n = blockIdx.x;
    const int tid = threadIdx.x;
#pragma unroll
    for (int k = 0; k < K_; ++k)
        ((float4*)l_s[k])[tid] = ((const float4*)(loss + (size_t)k * M_ + n * S_))[tid];
    __syncthreads();
    for (int s = tid; s < S_; s += 256) {
        float l[K_];
#pragma unroll
        for (int k = 0; k < K_; ++k) l[k] = l_s[k][s];
        int ord[K_] = {0, 1, 2, 3};
#pragma unroll
        for (int i = 1; i < K_; ++i) {
            const int v = ord[i];
            int j = i;
            while (j > 0 && l[ord[j - 1]] > l[v]) { ord[j] = ord[j - 1]; --j; }
            ord[j] = v;
        }
        ord_s[s] = (unsigned char)(ord[0] | (ord[1] << 2) | (ord[2] << 4) | (ord[3] << 6));
    }
    __syncthreads();
    if (tid == 0) {
        int tc[K_] = {0, 0, 0, 0};
        for (int s = 0; s < S_; ++s) {
            const unsigned b = ord_s[s];
            int ch = b & 3;
#pragma unroll
            for (int j = 0; j < K_; ++j) {
                const int m = (b >> (2 * j)) & 3;
                if (tc[m] < CAP_) { ch = m; break; }
            }
            ++tc[ch];
            chosen_buf[n * S_ + s] = ch;
            idx_out[n * S_ + s] = (float)ch;
        }
    }
}

// ----------------------------------------------------------------
extern "C" void kernel_launch(void* const* d_in, const int* in_sizes, int n_in,
                              void* d_out, int out_size, void* d_ws, size_t ws_size,
                              hipStream_t stream)
{
    const int*   x_in = (const int*)d_in[0];
    const int*   y    = (const int*)d_in[1];
    const float* tok  = (const float*)d_in[2];
    const float* pos  = (const float*)d_in[3];
    const float* ln1s = (const float*)d_in[4];
    const float* ln1b = (const float*)d_in[5];
    const float* Wqkv = (const float*)d_in[6];
    const float* bqkv = (const float*)d_in[7];
    const float* Wo   = (const float*)d_in[8];
    const float* bo   = (const float*)d_in[9];
    const float* ln2s = (const float*)d_in[10];
    const float* ln2b = (const float*)d_in[11];
    const float* W1   = (const float*)d_in[12];
    const float* b1   = (const float*)d_in[13];
    const float* W2   = (const float*)d_in[14];
    const float* b2   = (const float*)d_in[15];
    const float* lnfs = (const float*)d_in[16];
    const float* lnfb = (const float*)d_in[17];
    const float* Wcls = (const float*)d_in[18];
    const float* bcls = (const float*)d_in[19];
    const float* Wcnf = (const float*)d_in[20];
    const float* bcnf = (const float*)d_in[21];

    // ws layout (same as passing round-13):
    // R [M][1536] f32 (qkv f32 | mids bf16x3 [3][M][1024] | logits f32 [M][1000])
    // hs [3][M][512]bf16 | x [M][512]f32 | hfin [K][M][512]bf16 | (reserved) | loss [K][M]f32 | chosen [M]i32
    if (ws_size < 66142208) return;   // fail fast instead of corrupting
    float* R = (float*)d_ws;
    unsigned short* hs   = (unsigned short*)(R + (size_t)M_ * 1536);
    float* x             = (float*)(hs + 3 * HSPLANE);
    unsigned short* hfin = (unsigned short*)(x + (size_t)M_ * D_);
    unsigned short* Wt   = hfin + (size_t)K_ * M_ * D_;   // reserved (unused)
    float* loss          = (float*)(Wt + 3 * (size_t)524288);
    int*   chosen        = (int*)(loss + (size_t)K_ * M_);
    unsigned short* mids = (unsigned short*)R;            // mlp mid split planes (qkv dead then)
    const size_t midplane = (size_t)M_ * 1024;

    float* out      = (float*)d_out;                     // [N][S][C]
    float* conf_out = out + (size_t)M_ * C_;             // [N][K][S]
    float* idx_out  = conf_out + (size_t)N_ * K_ * S_;   // [N][S]

    for (int k = 0; k < K_; ++k) {
        embed_kernel<<<(M_ * (D_ / 4) + 255) / 256, 256, 0, stream>>>(
            x_in, tok + (size_t)k * V_ * D_, pos + (size_t)k * S_ * D_, x);
        for (int i = 0; i < NB_; ++i) {
            const size_t ki = (size_t)k * NB_ + i;
            ln_kernel<0><<<M_, 256, 0, stream>>>(x, ln1s + ki * D_, ln1b + ki * D_, hs, nullptr);
            gemm64f<0><<<dim3(24, 32), 256, 0, stream>>>(
                hs, HSPLANE, Wqkv + ki * D_ * 3 * D_, 3 * D_, bqkv + ki * 3 * D_,
                R, 0, 3 * D_, 3 * D_);
            attn_mfma_kernel<<<dim3(S_ / 64, NH_, N_), 256, 0, stream>>>(R, hs);
            gemm64f<1><<<dim3(8, 32), 256, 0, stream>>>(
                hs, HSPLANE, Wo + ki * D_ * D_, D_, bo + ki * D_, x, 0, D_, D_);
            ln_kernel<0><<<M_, 256, 0, stream>>>(x, ln2s + ki * D_, ln2b + ki * D_, hs, nullptr);
            for (int c = 0; c < 2; ++c) {   // MLP over two 1024-col mid chunks (mids in R; qkv dead)
                gemm64f<2><<<dim3(16, 32), 256, 0, stream>>>(
                    hs, HSPLANE, W1 + ki * D_ * HD_ + c * 1024, HD_, b1 + ki * HD_ + c * 1024,
                    mids, midplane, 1024, 1024);
                gemm64f<4><<<dim3(8, 32), 256, 0, stream>>>(
                    mids, midplane, W2 + ki * HD_ * D_ + (size_t)c * 1024 * D_, D_,
                    (c == 0) ? (b2 + ki * D_) : nullptr, x, 0, D_, D_);
            }
        }
        ln_kernel<1><<<M_, 256, 0, stream>>>(x, lnfs + (size_t)k * D_, lnfb + (size_t)k * D_,
                                             hs, hfin + (size_t)k * M_ * D_);
        gemm64f<0><<<dim3(16, 32), 256, 0, stream>>>(
            hs, HSPLANE, Wcls + (size_t)k * D_ * C_, C_, bcls + (size_t)k * C_, R, 0, C_, C_);
        conf_kernel<<<M_ / 4, 256, 0, stream>>>(hs, Wcnf + (size_t)k * D_, bcnf + k, conf_out, k);
        loss_kernel<<<M_, 256, 0, stream>>>(R, y, loss + (size_t)k * M_);
    }
    routing_kernel<<<N_, 256, 0, stream>>>(loss, idx_out, chosen);
    for (int k = 0; k < K_; ++k)
        rerun_kernel<<<dim3(16, 32), 256, 0, stream>>>(
            hfin + (size_t)k * M_ * D_, Wcls + (size_t)k * D_ * C_, bcls + (size_t)k * C_,
            chosen, k, out);
}

// Round 18
// 12358.853 us; speedup vs baseline: 1.4378x; 1.0320x over previous
//
#include <hip/hip_runtime.h>
#include <hip/hip_bf16.h>

#define N_  4
#define S_  1024
#define K_  4
#define V_  32000
#define C_  1000
#define D_  512
#define NH_ 8
#define NB_ 6
#define HD_ 2048
#define DH_ 64
#define CAP_ 256
#define M_  (N_*S_)   // 4096 rows

typedef __attribute__((ext_vector_type(8))) short short8_t;   // 8 bf16 = 4 VGPR
typedef __attribute__((ext_vector_type(4))) float f32x4_t;

#define MFMA16(a,b,c) __builtin_amdgcn_mfma_f32_16x16x32_bf16((a),(b),(c),0,0,0)

#define HSPLANE ((size_t)M_ * D_)        // elems per split plane of hs

static __device__ __forceinline__ float bfround(float v) {   // RNE to bf16, as float
    unsigned u = __float_as_uint(v);
    u = (u + 0x7FFFu + ((u >> 16) & 1u)) & 0xFFFF0000u;
    return __uint_as_float(u);
}
static __device__ __forceinline__ void split3(float v, unsigned short& a, unsigned short& b, unsigned short& c) {
    const float f0 = bfround(v);      const float r1 = v - f0;
    const float f1 = bfround(r1);     const float f2 = bfround(r1 - f1);
    a = (unsigned short)(__float_as_uint(f0) >> 16);
    b = (unsigned short)(__float_as_uint(f1) >> 16);
    c = (unsigned short)(__float_as_uint(f2) >> 16);
}
static __device__ __forceinline__ unsigned short f2bf(float f) {
    unsigned u = __float_as_uint(f);
    return (unsigned short)((u + 0x7FFFu + ((u >> 16) & 1u)) >> 16);
}
static __device__ __forceinline__ float b2f(unsigned short u) {
    return __uint_as_float((unsigned)u << 16);
}

// ---------------------------------------------------------------- embed
__global__ __launch_bounds__(256) void embed_kernel(const int* __restrict__ x_in,
    const float* __restrict__ tok, const float* __restrict__ pos, float* __restrict__ x)
{
    const int idx = blockIdx.x * 256 + threadIdx.x;
    const int total = M_ * (D_ / 4);
    if (idx >= total) return;
    const int d = (idx & (D_ / 4 - 1)) * 4;
    const int row = idx >> 7;
    const int s = row & (S_ - 1);
    const int t = x_in[row];
    const float4 a = *(const float4*)(tok + (size_t)t * D_ + d);
    const float4 b = *(const float4*)(pos + (size_t)s * D_ + d);
    float4 r; r.x = a.x + b.x; r.y = a.y + b.y; r.z = a.z + b.z; r.w = a.w + b.w;
    *(float4*)(x + (size_t)row * D_ + d) = r;
}

// ---------------------------------------------------------------- layernorm -> split bf16x3 planes (FIN: also write hfin plane0)
template<int FIN>
__global__ __launch_bounds__(256) void ln_kernel(const float* __restrict__ x,
    const float* __restrict__ sc, const float* __restrict__ bi, unsigned short* __restrict__ hs,
    unsigned short* __restrict__ hfin)
{
    const int row = blockIdx.x, tid = threadIdx.x;
    const float* xr = x + (size_t)row * D_;
    float v0 = xr[tid], v1 = xr[tid + 256];
    float s1 = v0 + v1;
#pragma unroll
    for (int off = 32; off; off >>= 1) s1 += __shfl_down(s1, off, 64);
    __shared__ float red[8];
    __shared__ float stat[2];
    const int wid = tid >> 6, lane = tid & 63;
    if (lane == 0) red[wid] = s1;
    __syncthreads();
    if (tid == 0) stat[0] = (red[0] + red[1] + red[2] + red[3]) * (1.f / (float)D_);
    __syncthreads();
    const float mean = stat[0];
    const float d0 = v0 - mean, d1 = v1 - mean;
    float s2 = d0 * d0 + d1 * d1;
#pragma unroll
    for (int off = 32; off; off >>= 1) s2 += __shfl_down(s2, off, 64);
    if (lane == 0) red[wid] = s2;
    __syncthreads();
    if (tid == 0) stat[1] = (red[0] + red[1] + red[2] + red[3]) * (1.f / (float)D_);
    __syncthreads();
    const float rstd = rsqrtf(stat[1] + 1e-5f);
    const float o0 = d0 * rstd * sc[tid] + bi[tid];
    const float o1 = d1 * rstd * sc[tid + 256] + bi[tid + 256];
    unsigned short a, b, c;
    const size_t base = (size_t)row * D_ + tid;
    split3(o0, a, b, c);
    hs[base] = a; hs[base + HSPLANE] = b; hs[base + 2 * HSPLANE] = c;
    if (FIN) hfin[base] = a;
    split3(o1, a, b, c);
    hs[base + 256] = a; hs[base + 256 + HSPLANE] = b; hs[base + 256 + 2 * HSPLANE] = c;
    if (FIN) hfin[base + 256] = a;
}

// ---------------------------------------------------------------- fp32-accurate GEMM via bf16x3: A pre-split direct-global,
// B staged from f32 weights with in-kernel split3. block 128x64, 4 waves of 64x32, XCD swizzle (nwg%8==0).
// Explicit software pipeline: next K-step's A-frags + B-row loaded into dedicated registers before the MFMA block.
// MODE: 0 = f32 store+bias (KD=512); 1 = f32 += (KD=512); 2 = gelu->split3 planes (KD=512); 4 = f32 += (KD=1024)
template<int MODE>
__global__ __launch_bounds__(256) void gemm64f(const unsigned short* __restrict__ A3, size_t aplane,
    const float* __restrict__ Bf, int ldb, const float* __restrict__ bias,
    void* __restrict__ Cv, size_t cplane, int Nc, int ldc)
{
    constexpr int KD = (MODE == 4) ? 1024 : 512;
    __shared__ __align__(16) unsigned short Bs[3][64][40];
    const int tid = threadIdx.x;
    const int gx = gridDim.x;
    const int nwg = gx * gridDim.y;
    const int bid = blockIdx.y * gx + blockIdx.x;
    const int cpx = nwg >> 3;
    const int swz = (bid & 7) * cpx + (bid >> 3);
    const int bm = (swz / gx) * 128, bn = (swz % gx) * 64;
    const int wid = tid >> 6, lane = tid & 63;
    const int wm = (wid >> 1) * 64, wn = (wid & 1) * 32;
    const int lr = lane & 15, lg = lane >> 4;
    const int scol = tid >> 2, skq = tid & 3;            // B staging: 2-way-free bank pattern
    const int gcol = bn + scol;
    const unsigned short* Ap0 = A3 + (size_t)(bm + wm + lr) * KD + lg * 8;

    f32x4_t acc[4][2] = {};

    // ---- prologue prefetch (k0 = 0)
    float bv[8];
    if (gcol < Nc) {
#pragma unroll
        for (int j = 0; j < 8; ++j) bv[j] = Bf[(size_t)(skq * 8 + j) * ldb + gcol];
    } else {
#pragma unroll
        for (int j = 0; j < 8; ++j) bv[j] = 0.f;
    }
    short8_t af[3][4];
#pragma unroll
    for (int m = 0; m < 4; ++m) {
        const unsigned short* ap = Ap0 + (size_t)m * 16 * KD;
        af[0][m] = *(const short8_t*)ap;
        af[1][m] = *(const short8_t*)(ap + aplane);
        af[2][m] = *(const short8_t*)(ap + 2 * aplane);
    }

#pragma unroll
    for (int k0 = 0; k0 < KD; k0 += 32) {
        unsigned short q0[8], q1[8], q2[8];
#pragma unroll
        for (int j = 0; j < 8; ++j) split3(bv[j], q0[j], q1[j], q2[j]);
        __syncthreads();   // previous iteration's Bs reads complete
        *(uint4*)&Bs[0][scol][skq * 8] = *(uint4*)&q0[0];
        *(uint4*)&Bs[1][scol][skq * 8] = *(uint4*)&q1[0];
        *(uint4*)&Bs[2][scol][skq * 8] = *(uint4*)&q2[0];
        __syncthreads();
        // ---- issue next K-step's global loads NOW; they fly under the MFMA block below
        float bvn[8];
        short8_t afn[3][4];
        if (k0 + 32 < KD) {
            const int k1 = k0 + 32;
            if (gcol < Nc) {
#pragma unroll
                for (int j = 0; j < 8; ++j) bvn[j] = Bf[(size_t)(k1 + skq * 8 + j) * ldb + gcol];
            } else {
#pragma unroll
                for (int j = 0; j < 8; ++j) bvn[j] = 0.f;
            }
#pragma unroll
            for (int m = 0; m < 4; ++m) {
                const unsigned short* ap = Ap0 + (size_t)m * 16 * KD + k1;
                afn[0][m] = *(const short8_t*)ap;
                afn[1][m] = *(const short8_t*)(ap + aplane);
                afn[2][m] = *(const short8_t*)(ap + 2 * aplane);
            }
        }
        short8_t bg[3][2];
#pragma unroll
        for (int s = 0; s < 3; ++s)
#pragma unroll
            for (int n2 = 0; n2 < 2; ++n2)
                bg[s][n2] = *(const short8_t*)&Bs[s][wn + n2 * 16 + lr][lg * 8];
#pragma unroll
        for (int m = 0; m < 4; ++m)
#pragma unroll
            for (int n2 = 0; n2 < 2; ++n2) {
                f32x4_t c = acc[m][n2];
                c = MFMA16(af[0][m], bg[0][n2], c);
                c = MFMA16(af[0][m], bg[1][n2], c);
                c = MFMA16(af[1][m], bg[0][n2], c);
                c = MFMA16(af[1][m], bg[1][n2], c);
                c = MFMA16(af[0][m], bg[2][n2], c);
                c = MFMA16(af[2][m], bg[0][n2], c);
                acc[m][n2] = c;
            }
        if (k0 + 32 < KD) {   // rotate pipeline registers
#pragma unroll
            for (int j = 0; j < 8; ++j) bv[j] = bvn[j];
#pragma unroll
            for (int m = 0; m < 4; ++m) {
                af[0][m] = afn[0][m];
                af[1][m] = afn[1][m];
                af[2][m] = afn[2][m];
            }
        }
    }
#pragma unroll
    for (int m = 0; m < 4; ++m)
#pragma unroll
        for (int n2 = 0; n2 < 2; ++n2) {
            const int col = bn + wn + n2 * 16 + lr;
            if (col >= Nc) continue;
            const float bv2 = bias ? bias[col] : 0.f;
            const int row0 = bm + wm + m * 16 + lg * 4;
#pragma unroll
            for (int r = 0; r < 4; ++r) {
                float v = acc[m][n2][r] + bv2;
                if (MODE == 2) {
                    const float t = v;
                    v = 0.5f * t * (1.f + tanhf(0.7978845608028654f * (t + 0.044715f * t * t * t)));
                    unsigned short a, b, c;
                    split3(v, a, b, c);
                    unsigned short* Cp = (unsigned short*)Cv + (size_t)(row0 + r) * ldc + col;
                    Cp[0] = a; Cp[cplane] = b; Cp[2 * cplane] = c;
                } else {
                    float* cp = (float*)Cv + (size_t)(row0 + r) * ldc + col;
                    if (MODE == 1 || MODE == 4) v += *cp;
                    *cp = v;
                }
            }
        }
}

// ---------------------------------------------------------------- masked classifier re-run (bf16 single product; W f32 in-kernel cast)
__global__ __launch_bounds__(256) void rerun_kernel(const unsigned short* __restrict__ A,
    const float* __restrict__ Wc, const float* __restrict__ bias,
    const int* __restrict__ chosen, const int kk, float* __restrict__ out)
{
    __shared__ int anyrow;
    const int tid = threadIdx.x;
    const int bm = blockIdx.y * 128, bn = blockIdx.x * 64;
    if (tid == 0) anyrow = 0;
    __syncthreads();
    if (tid < 128 && chosen[bm + tid] == kk) anyrow = 1;
    __syncthreads();
    if (!anyrow) return;
    const int wid = tid >> 6, lane = tid & 63;
    const int wm = (wid >> 1) * 64, wn = (wid & 1) * 32;
    const int lr = lane & 15, lg = lane >> 4;
    f32x4_t acc[4][2] = {};
#pragma unroll
    for (int k0 = 0; k0 < D_; k0 += 32) {
        short8_t af[4], bg[2];
#pragma unroll
        for (int m = 0; m < 4; ++m)
            af[m] = *(const short8_t*)(A + (size_t)(bm + wm + m * 16 + lr) * D_ + k0 + lg * 8);
#pragma unroll
        for (int n2 = 0; n2 < 2; ++n2) {
            const int col = bn + wn + n2 * 16 + lr;
            if (col < C_) {
#pragma unroll
                for (int j = 0; j < 8; ++j)
                    bg[n2][j] = (short)f2bf(Wc[(size_t)(k0 + lg * 8 + j) * C_ + col]);
            } else {
#pragma unroll
                for (int j = 0; j < 8; ++j) bg[n2][j] = 0;
            }
        }
#pragma unroll
        for (int m = 0; m < 4; ++m)
#pragma unroll
            for (int n2 = 0; n2 < 2; ++n2)
                acc[m][n2] = MFMA16(af[m], bg[n2], acc[m][n2]);
    }
#pragma unroll
    for (int m = 0; m < 4; ++m)
#pragma unroll
        for (int n2 = 0; n2 < 2; ++n2) {
            const int col = bn + wn + n2 * 16 + lr;
            if (col >= C_) continue;
            const float bv = bias[col];
            const int row0 = bm + wm + m * 16 + lg * 4;
#pragma unroll
            for (int r = 0; r < 4; ++r) {
                const int row = row0 + r;
                if (chosen[row] == kk) out[(size_t)row * C_ + col] = acc[m][n2][r] + bv;
            }
        }
}

// ---------------------------------------------------------------- MFMA flash attention (bf16x3 split in-kernel), split-bf16 output
// Round-18: K/V staging pipelined — next kt's global loads issue right after the staging barrier,
// flying under the QK^T + softmax + PV compute (same loads/split3/slots -> bit-identical).
__global__ __launch_bounds__(256) void attn_mfma_kernel(const float* __restrict__ qkv, unsigned short* __restrict__ hsO)
{
    __shared__ __align__(16) unsigned short Ks[3][32][72];
    __shared__ __align__(16) unsigned short Vt[3][64][40];
    __shared__ __align__(16) unsigned short Ps[4][3][16][40];
    const int qt = gridDim.x - 1 - blockIdx.x;   // descending: big causal blocks first
    const int hh = blockIdx.y, n = blockIdx.z;
    const int tid = threadIdx.x;
    const int w = tid >> 6, lane = tid & 63;
    const int lr = lane & 15, lg = lane >> 4;
    const size_t rs = 3 * D_;
    const float* base = qkv + (size_t)n * S_ * rs + hh * DH_;
    const int key = tid & 31, seg = tid >> 5;
    const int kswz = ((key & 3) ^ ((key >> 3) & 3));   // d-block permutation per key

    short8_t qf[3][2];
    {
        const int qrow = qt * 64 + w * 16 + lr;
#pragma unroll
        for (int ks = 0; ks < 2; ++ks) {
            const float* qp = base + (size_t)qrow * rs + ks * 32 + lg * 8;
            float v[8];
            *(float4*)&v[0] = ((const float4*)qp)[0];
            *(float4*)&v[4] = ((const float4*)qp)[1];
#pragma unroll
            for (int j = 0; j < 8; ++j) {
                unsigned short a, b, c;
                split3(v[j], a, b, c);
                qf[0][ks][j] = (short)a; qf[1][ks][j] = (short)b; qf[2][ks][j] = (short)c;
            }
        }
    }

    f32x4_t oacc[4] = {};
    float m_r[4], l_r[4];
#pragma unroll
    for (int r = 0; r < 4; ++r) { m_r[r] = -1e30f; l_r[r] = 0.f; }

    const int ktmax = 2 * qt + 2;

    // ---- prologue: load kt=0's K/V rows into registers
    float kv[8], vv[8];
    {
        const float* kp = base + (size_t)key * rs + D_ + seg * 8;
        const float* vp = kp + D_;
        *(float4*)&kv[0] = ((const float4*)kp)[0];
        *(float4*)&kv[4] = ((const float4*)kp)[1];
        *(float4*)&vv[0] = ((const float4*)vp)[0];
        *(float4*)&vv[4] = ((const float4*)vp)[1];
    }

    for (int kt = 0; kt < ktmax; ++kt) {
        // split current registers (no memory wait needed beyond what's already landed)
        unsigned short k0a[8], k1a[8], k2a[8], v0a[8], v1a[8], v2a[8];
#pragma unroll
        for (int j = 0; j < 8; ++j) split3(kv[j], k0a[j], k1a[j], k2a[j]);
#pragma unroll
        for (int j = 0; j < 8; ++j) split3(vv[j], v0a[j], v1a[j], v2a[j]);
        __syncthreads();   // previous iteration's Ks/Vt reads complete
        *(uint4*)&Ks[0][key][(seg ^ kswz) * 8] = *(uint4*)&k0a[0];
        *(uint4*)&Ks[1][key][(seg ^ kswz) * 8] = *(uint4*)&k1a[0];
        *(uint4*)&Ks[2][key][(seg ^ kswz) * 8] = *(uint4*)&k2a[0];
#pragma unroll
        for (int j = 0; j < 8; ++j) {
            Vt[0][seg * 8 + j][key] = v0a[j];
            Vt[1][seg * 8 + j][key] = v1a[j];
            Vt[2][seg * 8 + j][key] = v2a[j];
        }
        __syncthreads();
        // ---- issue next kt's K/V loads NOW; they fly under the compute below
        float kvn[8], vvn[8];
        if (kt + 1 < ktmax) {
            const float* kp = base + (size_t)((kt + 1) * 32 + key) * rs + D_ + seg * 8;
            const float* vp = kp + D_;
            *(float4*)&kvn[0] = ((const float4*)kp)[0];
            *(float4*)&kvn[4] = ((const float4*)kp)[1];
            *(float4*)&vvn[0] = ((const float4*)vp)[0];
            *(float4*)&vvn[4] = ((const float4*)vp)[1];
        }
        f32x4_t sacc[2] = {};
#pragma unroll
        for (int n2 = 0; n2 < 2; ++n2) {
            const int rk = n2 * 16 + lr;                       // key row being read
            const int rswz = ((rk & 3) ^ ((rk >> 3) & 3));
#pragma unroll
            for (int ks = 0; ks < 2; ++ks) {
                const int boff = ((ks * 4 + lg) ^ rswz) * 8;   // swizzled d-block offset
                short8_t kb0 = *(const short8_t*)&Ks[0][rk][boff];
                short8_t kb1 = *(const short8_t*)&Ks[1][rk][boff];
                short8_t kb2 = *(const short8_t*)&Ks[2][rk][boff];
                f32x4_t c = sacc[n2];
                c = MFMA16(qf[0][ks], kb0, c);
                c = MFMA16(qf[0][ks], kb1, c);
                c = MFMA16(qf[1][ks], kb0, c);
                c = MFMA16(qf[1][ks], kb1, c);
                c = MFMA16(qf[0][ks], kb2, c);
                c = MFMA16(qf[2][ks], kb0, c);
                sacc[n2] = c;
            }
        }
        float p[2][4];
#pragma unroll
        for (int n2 = 0; n2 < 2; ++n2)
#pragma unroll
            for (int r = 0; r < 4; ++r) {
                float s = sacc[n2][r] * 0.125f;
                const int kcol = kt * 32 + n2 * 16 + lr;
                const int qrow = qt * 64 + w * 16 + lg * 4 + r;
                if (kcol > qrow) s = -1e30f;
                p[n2][r] = s;
            }
        float scl[4];
#pragma unroll
        for (int r = 0; r < 4; ++r) {
            float tm = fmaxf(p[0][r], p[1][r]);
            tm = fmaxf(tm, __shfl_xor(tm, 1));
            tm = fmaxf(tm, __shfl_xor(tm, 2));
            tm = fmaxf(tm, __shfl_xor(tm, 4));
            tm = fmaxf(tm, __shfl_xor(tm, 8));
            const float mnew = fmaxf(m_r[r], tm);
            scl[r] = expf(m_r[r] - mnew);
            m_r[r] = mnew;
        }
#pragma unroll
        for (int r = 0; r < 4; ++r) {
            p[0][r] = expf(p[0][r] - m_r[r]);
            p[1][r] = expf(p[1][r] - m_r[r]);
            float ts = p[0][r] + p[1][r];
            ts += __shfl_xor(ts, 1);
            ts += __shfl_xor(ts, 2);
            ts += __shfl_xor(ts, 4);
            ts += __shfl_xor(ts, 8);
            l_r[r] = l_r[r] * scl[r] + ts;
        }
#pragma unroll
        for (int nf = 0; nf < 4; ++nf)
#pragma unroll
            for (int r = 0; r < 4; ++r) oacc[nf][r] *= scl[r];
#pragma unroll
        for (int n2 = 0; n2 < 2; ++n2)
#pragma unroll
            for (int r = 0; r < 4; ++r) {
                unsigned short a, b, c;
                split3(p[n2][r], a, b, c);
                Ps[w][0][lg * 4 + r][n2 * 16 + lr] = a;
                Ps[w][1][lg * 4 + r][n2 * 16 + lr] = b;
                Ps[w][2][lg * 4 + r][n2 * 16 + lr] = c;
            }
        short8_t pa0 = *(const short8_t*)&Ps[w][0][lr][lg * 8];
        short8_t pa1 = *(const short8_t*)&Ps[w][1][lr][lg * 8];
        short8_t pa2 = *(const short8_t*)&Ps[w][2][lr][lg * 8];
#pragma unroll
        for (int nf = 0; nf < 4; ++nf) {
            short8_t vb0 = *(const short8_t*)&Vt[0][nf * 16 + lr][lg * 8];
            short8_t vb1 = *(const short8_t*)&Vt[1][nf * 16 + lr][lg * 8];
            short8_t vb2 = *(const short8_t*)&Vt[2][nf * 16 + lr][lg * 8];
            f32x4_t c = oacc[nf];
            c = MFMA16(pa0, vb0, c);
            c = MFMA16(pa0, vb1, c);
            c = MFMA16(pa1, vb0, c);
            c = MFMA16(pa1, vb1, c);
            c = MFMA16(pa0, vb2, c);
            c = MFMA16(pa2, vb0, c);
            oacc[nf] = c;
        }
        if (kt + 1 < ktmax) {   // rotate pipeline registers
#pragma unroll
            for (int j = 0; j < 8; ++j) { kv[j] = kvn[j]; vv[j] = vvn[j]; }
        }
    }
    float inv[4];
#pragma unroll
    for (int r = 0; r < 4; ++r) inv[r] = 1.f / l_r[r];
#pragma unroll
    for (int nf = 0; nf < 4; ++nf)
#pragma unroll
        for (int r = 0; r < 4; ++r) {
            const int qrow = qt * 64 + w * 16 + lg * 4 + r;
            const size_t idx = ((size_t)n * S_ + qrow) * D_ + hh * DH_ + nf * 16 + lr;
            unsigned short a, b, c;
            split3(oacc[nf][r] * inv[r], a, b, c);
            hsO[idx] = a; hsO[idx + HSPLANE] = b; hsO[idx + 2 * HSPLANE] = c;
        }
}

// ---------------------------------------------------------------- confidence head (reads split planes 0+1)
__global__ __launch_bounds__(256) void conf_kernel(const unsigned short* __restrict__ hs,
    const float* __restrict__ w, const float* __restrict__ bc, float* __restrict__ conf_out, int k)
{
    const int wid = threadIdx.x >> 6, lane = threadIdx.x & 63;
    const int row = blockIdx.x * 4 + wid;
    const unsigned short* h0 = hs + (size_t)row * D_;
    const unsigned short* h1 = h0 + HSPLANE;
    float sm = 0.f;
#pragma unroll
    for (int j = 0; j < 8; ++j) {
        const int i = lane + 64 * j;
        sm += (b2f(h0[i]) + b2f(h1[i])) * w[i];
    }
#pragma unroll
    for (int off = 32; off; off >>= 1) sm += __shfl_down(sm, off, 64);
    if (lane == 0) {
        const int n = row >> 10, s = row & (S_ - 1);
        conf_out[((size_t)n * K_ + k) * S_ + s] = sm + bc[0];
    }
}

// ---------------------------------------------------------------- per-token CE loss
__global__ __launch_bounds__(256) void loss_kernel(const float* __restrict__ logits,
    const int* __restrict__ y, float* __restrict__ loss)
{
    const int row = blockIdx.x;
    const float* lr = logits + (size_t)row * C_;
    const int tid = threadIdx.x;
    __shared__ float red[256];
    float mx = -1e30f;
    for (int c = tid; c < C_; c += 256) mx = fmaxf(mx, lr[c]);
    red[tid] = mx; __syncthreads();
    for (int st = 128; st > 0; st >>= 1) {
        if (tid < st) red[tid] = fmaxf(red[tid], red[tid + st]);
        __syncthreads();
    }
    mx = red[0];
    __syncthreads();
    float sm = 0.f;
    for (int c = tid; c < C_; c += 256) sm += expf(lr[c] - mx);
    red[tid] = sm; __syncthreads();
    for (int st = 128; st > 0; st >>= 1) {
        if (tid < st) red[tid] += red[tid + st];
        __syncthreads();
    }
    if (tid == 0) loss[row] = logf(red[0]) + mx - lr[y[row]];
}

// ---------------------------------------------------------------- capacity auction: LDS-staged, pre-sorted
__global__ __launch_bounds__(256) void routing_kernel(const float* __restrict__ loss,
    float* __restrict__ idx_out, int* __restrict__ chosen_buf)
{
    __shared__ float l_s[K_][S_];
    __shared__ unsigned char ord_s[S_];
    const int n = blockIdx.x;
    const int tid = threadIdx.x;
#pragma unroll
    for (int k = 0; k < K_; ++k)
        ((float4*)l_s[k])[tid] = ((const float4*)(loss + (size_t)k * M_ + n * S_))[tid];
    __syncthreads();
    for (int s = tid; s < S_; s += 256) {
        float l[K_];
#pragma unroll
        for (int k = 0; k < K_; ++k) l[k] = l_s[k][s];
        int ord[K_] = {0, 1, 2, 3};
#pragma unroll
        for (int i = 1; i < K_; ++i) {
            const int v = ord[i];
            int j = i;
            while (j > 0 && l[ord[j - 1]] > l[v]) { ord[j] = ord[j - 1]; --j; }
            ord[j] = v;
        }
        ord_s[s] = (unsigned char)(ord[0] | (ord[1] << 2) | (ord[2] << 4) | (ord[3] << 6));
    }
    __syncthreads();
    if (tid == 0) {
        int tc[K_] = {0, 0, 0, 0};
        for (int s = 0; s < S_; ++s) {
            const unsigned b = ord_s[s];
            int ch = b & 3;
#pragma unroll
            for (int j = 0; j < K_; ++j) {
                const int m = (b >> (2 * j)) & 3;
                if (tc[m] < CAP_) { ch = m; break; }
            }
            ++tc[ch];
            chosen_buf[n * S_ + s] = ch;
            idx_out[n * S_ + s] = (float)ch;
        }
    }
}

// ----------------------------------------------------------------
extern "C" void kernel_launch(void* const* d_in, const int* in_sizes, int n_in,
                              void* d_out, int out_size, void* d_ws, size_t ws_size,
                              hipStream_t stream)
{
    const int*   x_in = (const int*)d_in[0];
    const int*   y    = (const int*)d_in[1];
    const float* tok  = (const float*)d_in[2];
    const float* pos  = (const float*)d_in[3];
    const float* ln1s = (const float*)d_in[4];
    const float* ln1b = (const float*)d_in[5];
    const float* Wqkv = (const float*)d_in[6];
    const float* bqkv = (const float*)d_in[7];
    const float* Wo   = (const float*)d_in[8];
    const float* bo   = (const float*)d_in[9];
    const float* ln2s = (const float*)d_in[10];
    const float* ln2b = (const float*)d_in[11];
    const float* W1   = (const float*)d_in[12];
    const float* b1   = (const float*)d_in[13];
    const float* W2   = (const float*)d_in[14];
    const float* b2   = (const float*)d_in[15];
    const float* lnfs = (const float*)d_in[16];
    const float* lnfb = (const float*)d_in[17];
    const float* Wcls = (const float*)d_in[18];
    const float* bcls = (const float*)d_in[19];
    const float* Wcnf = (const float*)d_in[20];
    const float* bcnf = (const float*)d_in[21];

    // ws layout (same as passing round-13):
    // R [M][1536] f32 (qkv f32 | mids bf16x3 [3][M][1024] | logits f32 [M][1000])
    // hs [3][M][512]bf16 | x [M][512]f32 | hfin [K][M][512]bf16 | (reserved) | loss [K][M]f32 | chosen [M]i32
    if (ws_size < 66142208) return;   // fail fast instead of corrupting
    float* R = (float*)d_ws;
    unsigned short* hs   = (unsigned short*)(R + (size_t)M_ * 1536);
    float* x             = (float*)(hs + 3 * HSPLANE);
    unsigned short* hfin = (unsigned short*)(x + (size_t)M_ * D_);
    unsigned short* Wt   = hfin + (size_t)K_ * M_ * D_;   // reserved (unused)
    float* loss          = (float*)(Wt + 3 * (size_t)524288);
    int*   chosen        = (int*)(loss + (size_t)K_ * M_);
    unsigned short* mids = (unsigned short*)R;            // mlp mid split planes (qkv dead then)
    const size_t midplane = (size_t)M_ * 1024;

    float* out      = (float*)d_out;                     // [N][S][C]
    float* conf_out = out + (size_t)M_ * C_;             // [N][K][S]
    float* idx_out  = conf_out + (size_t)N_ * K_ * S_;   // [N][S]

    for (int k = 0; k < K_; ++k) {
        embed_kernel<<<(M_ * (D_ / 4) + 255) / 256, 256, 0, stream>>>(
            x_in, tok + (size_t)k * V_ * D_, pos + (size_t)k * S_ * D_, x);
        for (int i = 0; i < NB_; ++i) {
            const size_t ki = (size_t)k * NB_ + i;
            ln_kernel<0><<<M_, 256, 0, stream>>>(x, ln1s + ki * D_, ln1b + ki * D_, hs, nullptr);
            gemm64f<0><<<dim3(24, 32), 256, 0, stream>>>(
                hs, HSPLANE, Wqkv + ki * D_ * 3 * D_, 3 * D_, bqkv + ki * 3 * D_,
                R, 0, 3 * D_, 3 * D_);
            attn_mfma_kernel<<<dim3(S_ / 64, NH_, N_), 256, 0, stream>>>(R, hs);
            gemm64f<1><<<dim3(8, 32), 256, 0, stream>>>(
                hs, HSPLANE, Wo + ki * D_ * D_, D_, bo + ki * D_, x, 0, D_, D_);
            ln_kernel<0><<<M_, 256, 0, stream>>>(x, ln2s + ki * D_, ln2b + ki * D_, hs, nullptr);
            for (int c = 0; c < 2; ++c) {   // MLP over two 1024-col mid chunks (mids in R; qkv dead)
                gemm64f<2><<<dim3(16, 32), 256, 0, stream>>>(
                    hs, HSPLANE, W1 + ki * D_ * HD_ + c * 1024, HD_, b1 + ki * HD_ + c * 1024,
                    mids, midplane, 1024, 1024);
                gemm64f<4><<<dim3(8, 32), 256, 0, stream>>>(
                    mids, midplane, W2 + ki * HD_ * D_ + (size_t)c * 1024 * D_, D_,
                    (c == 0) ? (b2 + ki * D_) : nullptr, x, 0, D_, D_);
            }
        }
        ln_kernel<1><<<M_, 256, 0, stream>>>(x, lnfs + (size_t)k * D_, lnfb + (size_t)k * D_,
                                             hs, hfin + (size_t)k * M_ * D_);
        gemm64f<0><<<dim3(16, 32), 256, 0, stream>>>(
            hs, HSPLANE, Wcls + (size_t)k * D_ * C_, C_, bcls + (size_t)k * C_, R, 0, C_, C_);
        conf_kernel<<<M_ / 4, 256, 0, stream>>>(hs, Wcnf + (size_t)k * D_, bcnf + k, conf_out, k);
        loss_kernel<<<M_, 256, 0, stream>>>(R, y, loss + (size_t)k * M_);
    }
    routing_kernel<<<N_, 256, 0, stream>>>(loss, idx_out, chosen);
    for (int k = 0; k < K_; ++k)
        rerun_kernel<<<dim3(16, 32), 256, 0, stream>>>(
            hfin + (size_t)k * M_ * D_, Wcls + (size_t)k * D_ * C_, bcls + (size_t)k * C_,
            chosen, k, out);
}